// Round 4
// baseline (7560.873 us; speedup 1.0000x reference)
//
#include <hip/hip_runtime.h>

// Problem dims (fixed)
#define NB 4096   // B
#define NL 7      // L
#define ND 1024   // D
#define NH 1024   // H
#define NT 6      // T
#define NSTEP 5   // effective scan steps (t = 0..4)
#define GAP 0.02f // gumbel top-2 gap below which we recompute the row in fp32

typedef __attribute__((ext_vector_type(8))) short bf16x8;
typedef __attribute__((ext_vector_type(4))) float f32x4;

// ---------------- threefry2x32 (JAX-compatible, 20 rounds) ----------------
__device__ __forceinline__ unsigned rotl32(unsigned x, int r) {
  return (x << r) | (x >> (32 - r));
}

__device__ __forceinline__ void threefry2x32(unsigned k0, unsigned k1,
                                             unsigned x0, unsigned x1,
                                             unsigned& o0, unsigned& o1) {
  unsigned ks2 = k0 ^ k1 ^ 0x1BD11BDAu;
#define TFR(R) { x0 += x1; x1 = rotl32(x1, (R)); x1 ^= x0; }
  x0 += k0; x1 += k1;
  TFR(13) TFR(15) TFR(26) TFR(6)
  x0 += k1; x1 += ks2 + 1u;
  TFR(17) TFR(29) TFR(16) TFR(24)
  x0 += ks2; x1 += k0 + 2u;
  TFR(13) TFR(15) TFR(26) TFR(6)
  x0 += k0; x1 += k1 + 3u;
  TFR(17) TFR(29) TFR(16) TFR(24)
  x0 += k1; x1 += ks2 + 4u;
  TFR(13) TFR(15) TFR(26) TFR(6)
  x0 += ks2; x1 += k0 + 5u;
#undef TFR
  o0 = x0; o1 = x1;
}

__device__ __forceinline__ float gumbel_for(int b, int j) {
  unsigned o0, o1;
  threefry2x32(0u, 42u, 0u, (unsigned)(b * 28 + j), o0, o1);
  unsigned bits = o0 ^ o1;
  const float TINY = 1.17549435e-38f;
  float u = __uint_as_float((bits >> 9) | 0x3f800000u) - 1.0f;
  u = fmaxf(TINY, u + TINY);
  return -logf(-logf(u));
}

// ---------------- bf16 hi/lo split ----------------
__device__ __forceinline__ unsigned short f2bf(float f) {
  unsigned u = __float_as_uint(f);
  unsigned r = u + 0x7FFFu + ((u >> 16) & 1u);
  return (unsigned short)(r >> 16);
}
__device__ __forceinline__ float bf2f(unsigned short h) {
  return __uint_as_float(((unsigned)h) << 16);
}

__global__ __launch_bounds__(256) void k_split(
    const float* __restrict__ x, unsigned short* __restrict__ hi,
    unsigned short* __restrict__ lo) {
  const size_t i = ((size_t)blockIdx.x * 256 + threadIdx.x) * 4;
  float4 v = *(const float4*)(x + i);
  ushort4 h, l;
  h.x = f2bf(v.x); l.x = f2bf(v.x - bf2f(h.x));
  h.y = f2bf(v.y); l.y = f2bf(v.y - bf2f(h.y));
  h.z = f2bf(v.z); l.z = f2bf(v.z - bf2f(h.z));
  h.w = f2bf(v.w); l.w = f2bf(v.w - bf2f(h.w));
  *(ushort4*)(hi + i) = h;
  *(ushort4*)(lo + i) = l;
}

// ---------------- shared 64x64 fp32 tile core (gemm_bias only) ------
__device__ __forceinline__ void tile_compute(const float (*As)[68],
                                             const float (*Bs)[68],
                                             float acc[4][4], int tx, int ty) {
#pragma unroll
  for (int kk = 0; kk < 16; ++kk) {
    float4 a  = *(const float4*)&As[kk][ty * 4];
    float4 bb = *(const float4*)&Bs[kk][tx * 4];
    acc[0][0] += a.x * bb.x; acc[0][1] += a.x * bb.y; acc[0][2] += a.x * bb.z; acc[0][3] += a.x * bb.w;
    acc[1][0] += a.y * bb.x; acc[1][1] += a.y * bb.y; acc[1][2] += a.y * bb.z; acc[1][3] += a.y * bb.w;
    acc[2][0] += a.z * bb.x; acc[2][1] += a.z * bb.y; acc[2][2] += a.z * bb.z; acc[2][3] += a.z * bb.w;
    acc[3][0] += a.w * bb.x; acc[3][1] += a.w * bb.y; acc[3][2] += a.w * bb.z; acc[3][3] += a.w * bb.w;
  }
}

#define TILE_DECLS \
  __shared__ float As[16][68]; \
  __shared__ float Bs[16][68]; \
  float acc[4][4] = {}; \
  const int tid = threadIdx.x; \
  const int tx = tid & 15, ty = tid >> 4; \
  const int row0 = blockIdx.y * 64, col0 = blockIdx.x * 64; \
  const int lm = tid >> 2; \
  const int lk4 = (tid & 3) * 4;

#define STORE_AS(av) { As[lk4+0][lm]=(av).x; As[lk4+1][lm]=(av).y; As[lk4+2][lm]=(av).z; As[lk4+3][lm]=(av).w; }
#define STORE_BS(bv) { Bs[lk4+0][lm]=(bv).x; Bs[lk4+1][lm]=(bv).y; Bs[lk4+2][lm]=(bv).z; Bs[lk4+3][lm]=(bv).w; }

// ---------------- C = A @ Bw^T + bias (A optionally gathered) -- fp32 -----
__global__ __launch_bounds__(256) void gemm_bias(
    const float* __restrict__ A, const int* __restrict__ gidx,
    const float* __restrict__ enc, const float* __restrict__ Bw,
    const float* __restrict__ bias, float* __restrict__ C) {
  TILE_DECLS
  const int r = row0 + lm;
  const float* arow = gidx ? (enc + (((size_t)r * NL + gidx[r]) << 10))
                           : (A + ((size_t)r << 10));
  const float* brow = Bw + ((size_t)(col0 + lm) << 10);
  for (int k0 = 0; k0 < ND; k0 += 16) {
    float4 av = *(const float4*)(arow + k0 + lk4);
    STORE_AS(av)
    float4 bv = *(const float4*)(brow + k0 + lk4);
    STORE_BS(bv)
    __syncthreads();
    tile_compute(As, Bs, acc, tx, ty);
    __syncthreads();
  }
#pragma unroll
  for (int i = 0; i < 4; ++i) {
    const int rr = row0 + ty * 4 + i;
    const int n0 = col0 + tx * 4;
    float4 v = make_float4(acc[i][0] + bias[n0 + 0], acc[i][1] + bias[n0 + 1],
                           acc[i][2] + bias[n0 + 2], acc[i][3] + bias[n0 + 3]);
    *(float4*)(C + ((size_t)rr << 10) + n0) = v;
  }
}

// ---------------- classify rows (t,b) by tt ----------------
__global__ __launch_bounds__(256) void k_classify(
    const int* __restrict__ xes, int* __restrict__ cls_cnt,
    int* __restrict__ l0, int* __restrict__ l1) {
  const int r = blockIdx.x * 256 + threadIdx.x;
  if (r >= NSTEP * NB) return;
  const int b = r & (NB - 1), t = r >> 12;
  const int tt = xes[(b * NT + t) * 3 + 2];
  if (tt == 0) { int p = atomicAdd(&cls_cnt[0], 1); l0[p] = r; }
  else         { int p = atomicAdd(&cls_cnt[1], 1); l1[p] = r; }
}

// ---------------- G1 (bf16 MFMA): edges, K=2048 per class ----------------
// class0 (tt==0): edge = h@Wh^T + v@Wv^T   -> segs 0,1 of w4
// class1        : edge = h@Wsh^T + v@Wsv^T -> segs 2,3 of w4
// Outputs: packed bf16 hi|lo plane ehilo[r][n] and fp32 edge4 (t=4 slice).
__global__ __launch_bounds__(256) void g1_mfma(
    const int* __restrict__ cls_cnt, const int* __restrict__ l0,
    const int* __restrict__ l1, const int* __restrict__ xes,
    const unsigned short* __restrict__ enc_hi, const unsigned short* __restrict__ enc_lo,
    const unsigned short* __restrict__ w4hi, const unsigned short* __restrict__ w4lo,
    unsigned* __restrict__ ehilo, float* __restrict__ edge4) {
  const int n0c = cls_cnt[0], n1c = cls_cnt[1];
  const int tiles0 = (n0c + 127) >> 7, tiles1 = (n1c + 127) >> 7;
  const int bx = blockIdx.x;
  if (bx >= tiles0 + tiles1) return;
  int cls, mtile, nc;
  const int* list;
  if (bx < tiles0) { cls = 0; mtile = bx; nc = n0c; list = l0; }
  else { cls = 1; mtile = bx - tiles0; nc = n1c; list = l1; }

  __shared__ unsigned short sAhi[4096], sAlo[4096], sBhi[4096], sBlo[4096];
  const int tid = threadIdx.x;
  const int ncol0 = blockIdx.y * 128;

  // staging indices: two 16B slots per thread per plane; same row both slots
  const int ri = tid & 127;
  const int c0 = tid >> 7;        // 0..1
  const int c1 = c0 + 2;          // 2..3
  const int li = mtile * 128 + ri;
  const int rsrc = list[(li < nc) ? li : (nc - 1)];
  const int b = rsrc & (NB - 1), t = rsrc >> 12;
  const int hidx = xes[(b * NT + t) * 3 + 0];
  const int vidx = xes[(b * NT + t) * 3 + 1];
  const unsigned short* ha = enc_hi + (((size_t)b * NL + hidx) << 10);
  const unsigned short* la = enc_lo + (((size_t)b * NL + hidx) << 10);
  const unsigned short* hb = enc_hi + (((size_t)b * NL + vidx) << 10);
  const unsigned short* lb = enc_lo + (((size_t)b * NL + vidx) << 10);
  const size_t wrow = ((size_t)(ncol0 + ri)) << 10;

  const int wave = tid >> 6, lane = tid & 63;
  const int wm = wave >> 1, wn = wave & 1;
  const int q = lane >> 4, m16 = lane & 15;

  f32x4 acc[4][4] = {};

  for (int kt = 0; kt < 64; ++kt) {
    const int seg = (kt < 32) ? (cls * 2) : (cls * 2 + 1);
    const int kl = (kt & 31) * 32;
    const unsigned short* ah = (kt < 32) ? ha : hb;
    const unsigned short* al = (kt < 32) ? la : lb;
    bf16x8 vah0 = *(const bf16x8*)(ah + kl + c0 * 8);
    bf16x8 vah1 = *(const bf16x8*)(ah + kl + c1 * 8);
    bf16x8 val0 = *(const bf16x8*)(al + kl + c0 * 8);
    bf16x8 val1 = *(const bf16x8*)(al + kl + c1 * 8);
    const unsigned short* wh = w4hi + (((size_t)seg) << 20) + wrow + kl;
    const unsigned short* wl = w4lo + (((size_t)seg) << 20) + wrow + kl;
    bf16x8 vbh0 = *(const bf16x8*)(wh + c0 * 8);
    bf16x8 vbh1 = *(const bf16x8*)(wh + c1 * 8);
    bf16x8 vbl0 = *(const bf16x8*)(wl + c0 * 8);
    bf16x8 vbl1 = *(const bf16x8*)(wl + c1 * 8);
    *(bf16x8*)&sAhi[(c0 * 128 + ri) * 8] = vah0;
    *(bf16x8*)&sAhi[(c1 * 128 + ri) * 8] = vah1;
    *(bf16x8*)&sAlo[(c0 * 128 + ri) * 8] = val0;
    *(bf16x8*)&sAlo[(c1 * 128 + ri) * 8] = val1;
    *(bf16x8*)&sBhi[(c0 * 128 + ri) * 8] = vbh0;
    *(bf16x8*)&sBhi[(c1 * 128 + ri) * 8] = vbh1;
    *(bf16x8*)&sBlo[(c0 * 128 + ri) * 8] = vbl0;
    *(bf16x8*)&sBlo[(c1 * 128 + ri) * 8] = vbl1;
    __syncthreads();

    bf16x8 bh[4], bl[4];
#pragma unroll
    for (int tn = 0; tn < 4; ++tn) {
      const int nl = wn * 64 + tn * 16 + m16;
      bh[tn] = *(const bf16x8*)&sBhi[(q * 128 + nl) * 8];
      bl[tn] = *(const bf16x8*)&sBlo[(q * 128 + nl) * 8];
    }
#pragma unroll
    for (int tm = 0; tm < 4; ++tm) {
      const int ml = wm * 64 + tm * 16 + m16;
      bf16x8 ah8 = *(const bf16x8*)&sAhi[(q * 128 + ml) * 8];
      bf16x8 al8 = *(const bf16x8*)&sAlo[(q * 128 + ml) * 8];
#pragma unroll
      for (int tn = 0; tn < 4; ++tn) {
        acc[tm][tn] = __builtin_amdgcn_mfma_f32_16x16x32_bf16(ah8, bh[tn], acc[tm][tn], 0, 0, 0);
        acc[tm][tn] = __builtin_amdgcn_mfma_f32_16x16x32_bf16(al8, bh[tn], acc[tm][tn], 0, 0, 0);
        acc[tm][tn] = __builtin_amdgcn_mfma_f32_16x16x32_bf16(ah8, bl[tn], acc[tm][tn], 0, 0, 0);
      }
    }
    __syncthreads();
  }

  // epilogue: store packed bf16 hi|lo (+ fp32 for t=4 rows)
#pragma unroll
  for (int tm = 0; tm < 4; ++tm) {
#pragma unroll
    for (int j = 0; j < 4; ++j) {
      const int rl = wm * 64 + tm * 16 + q * 4 + j;
      const int li2 = mtile * 128 + rl;
      if (li2 < nc) {
        const int rr = list[li2];
#pragma unroll
        for (int tn = 0; tn < 4; ++tn) {
          const int n = ncol0 + wn * 64 + tn * 16 + m16;
          const float val = acc[tm][tn][j];
          unsigned short h = f2bf(val);
          unsigned short l = f2bf(val - bf2f(h));
          ehilo[(size_t)rr * NH + n] = (unsigned)h | ((unsigned)l << 16);
          if (rr >= 4 * NB) edge4[(size_t)(rr - 4 * NB) * NH + n] = val;
        }
      }
    }
  }
}

// ---------------- G2 (bf16 MFMA): st = max(0, max_t edge@We^T) ------------
__global__ __launch_bounds__(256) void g2_mfma(
    const unsigned* __restrict__ ehilo,
    const unsigned short* __restrict__ wehi, const unsigned short* __restrict__ welo,
    unsigned* __restrict__ st) {
  __shared__ unsigned short sAhi[4096], sAlo[4096], sBhi[4096], sBlo[4096];
  const int tid = threadIdx.x;
  const int row0 = blockIdx.x * 128;
  const int ncol0 = blockIdx.y * 128;

  const int ri = tid & 127;
  const int c0 = tid >> 7;
  const int c1 = c0 + 2;
  const size_t arow = (size_t)(row0 + ri) * NH;
  const size_t wrow = ((size_t)(ncol0 + ri)) << 10;

  const int wave = tid >> 6, lane = tid & 63;
  const int wm = wave >> 1, wn = wave & 1;
  const int q = lane >> 4, m16 = lane & 15;

  f32x4 acc[4][4] = {};

  for (int kt = 0; kt < 32; ++kt) {
    const int kl = kt * 32;
    // unpack packed edge planes (hi in low16, lo in high16)
    uint4 p00 = *(const uint4*)(ehilo + arow + kl + c0 * 8);
    uint4 p01 = *(const uint4*)(ehilo + arow + kl + c0 * 8 + 4);
    uint4 p10 = *(const uint4*)(ehilo + arow + kl + c1 * 8);
    uint4 p11 = *(const uint4*)(ehilo + arow + kl + c1 * 8 + 4);
    bf16x8 ah0, al0, ah1, al1;
    {
      unsigned u[8] = {p00.x, p00.y, p00.z, p00.w, p01.x, p01.y, p01.z, p01.w};
#pragma unroll
      for (int i = 0; i < 8; ++i) { ah0[i] = (short)(u[i] & 0xffff); al0[i] = (short)(u[i] >> 16); }
      unsigned v[8] = {p10.x, p10.y, p10.z, p10.w, p11.x, p11.y, p11.z, p11.w};
#pragma unroll
      for (int i = 0; i < 8; ++i) { ah1[i] = (short)(v[i] & 0xffff); al1[i] = (short)(v[i] >> 16); }
    }
    bf16x8 vbh0 = *(const bf16x8*)(wehi + wrow + kl + c0 * 8);
    bf16x8 vbh1 = *(const bf16x8*)(wehi + wrow + kl + c1 * 8);
    bf16x8 vbl0 = *(const bf16x8*)(welo + wrow + kl + c0 * 8);
    bf16x8 vbl1 = *(const bf16x8*)(welo + wrow + kl + c1 * 8);
    *(bf16x8*)&sAhi[(c0 * 128 + ri) * 8] = ah0;
    *(bf16x8*)&sAhi[(c1 * 128 + ri) * 8] = ah1;
    *(bf16x8*)&sAlo[(c0 * 128 + ri) * 8] = al0;
    *(bf16x8*)&sAlo[(c1 * 128 + ri) * 8] = al1;
    *(bf16x8*)&sBhi[(c0 * 128 + ri) * 8] = vbh0;
    *(bf16x8*)&sBhi[(c1 * 128 + ri) * 8] = vbh1;
    *(bf16x8*)&sBlo[(c0 * 128 + ri) * 8] = vbl0;
    *(bf16x8*)&sBlo[(c1 * 128 + ri) * 8] = vbl1;
    __syncthreads();

    bf16x8 bh[4], bl[4];
#pragma unroll
    for (int tn = 0; tn < 4; ++tn) {
      const int nl = wn * 64 + tn * 16 + m16;
      bh[tn] = *(const bf16x8*)&sBhi[(q * 128 + nl) * 8];
      bl[tn] = *(const bf16x8*)&sBlo[(q * 128 + nl) * 8];
    }
#pragma unroll
    for (int tm = 0; tm < 4; ++tm) {
      const int ml = wm * 64 + tm * 16 + m16;
      bf16x8 ah8 = *(const bf16x8*)&sAhi[(q * 128 + ml) * 8];
      bf16x8 al8 = *(const bf16x8*)&sAlo[(q * 128 + ml) * 8];
#pragma unroll
      for (int tn = 0; tn < 4; ++tn) {
        acc[tm][tn] = __builtin_amdgcn_mfma_f32_16x16x32_bf16(ah8, bh[tn], acc[tm][tn], 0, 0, 0);
        acc[tm][tn] = __builtin_amdgcn_mfma_f32_16x16x32_bf16(al8, bh[tn], acc[tm][tn], 0, 0, 0);
        acc[tm][tn] = __builtin_amdgcn_mfma_f32_16x16x32_bf16(ah8, bl[tn], acc[tm][tn], 0, 0, 0);
      }
    }
    __syncthreads();
  }

#pragma unroll
  for (int tm = 0; tm < 4; ++tm) {
#pragma unroll
    for (int j = 0; j < 4; ++j) {
      const int rr = row0 + wm * 64 + tm * 16 + q * 4 + j;
      const int b = rr & (NB - 1);
#pragma unroll
      for (int tn = 0; tn < 4; ++tn) {
        const int n = ncol0 + wn * 64 + tn * 16 + m16;
        unsigned val = __float_as_uint(fmaxf(acc[tm][tn][j], 0.f));
        atomicMax(&st[(size_t)b * NH + n], val);
      }
    }
  }
}

// ---------------- G5 (bf16 MFMA): fused ctx GEMM + tanh + V4 reduce --------
__global__ __launch_bounds__(256) void g5_mfma(
    const unsigned short* __restrict__ Ahi, const unsigned short* __restrict__ Alo,
    const unsigned short* __restrict__ Bhi, const unsigned short* __restrict__ Blo,
    const float* __restrict__ inp, const float* __restrict__ bc,
    const float* __restrict__ V4, float* __restrict__ att) {
  __shared__ unsigned short sAhi[4096], sAlo[4096], sBhi[4096], sBlo[4096];
  __shared__ float red[128][32];

  const int tid = threadIdx.x;
  const int row0 = blockIdx.x * 128;   // M-tile (224)
  const int ncol0 = blockIdx.y * 128;  // N-tile (32)

  const int s0 = tid, s1 = tid + 256;
  const int c0 = s0 >> 7, r0 = s0 & 127;
  const int c1 = s1 >> 7, r1 = s1 & 127;
  size_t aoff0 = (size_t)(row0 + r0) * ND + c0 * 8;
  size_t aoff1 = (size_t)(row0 + r1) * ND + c1 * 8;
  size_t boff0 = (size_t)(ncol0 + r0) * ND + c0 * 8;
  size_t boff1 = (size_t)(ncol0 + r1) * ND + c1 * 8;

  const int wave = tid >> 6, lane = tid & 63;
  const int wm = wave >> 1, wn = wave & 1;
  const int q = lane >> 4, m16 = lane & 15;

  f32x4 acc[4][4] = {};

  for (int kt = 0; kt < 32; ++kt) {
    bf16x8 vah0 = *(const bf16x8*)(Ahi + aoff0);
    bf16x8 vah1 = *(const bf16x8*)(Ahi + aoff1);
    bf16x8 val0 = *(const bf16x8*)(Alo + aoff0);
    bf16x8 val1 = *(const bf16x8*)(Alo + aoff1);
    bf16x8 vbh0 = *(const bf16x8*)(Bhi + boff0);
    bf16x8 vbh1 = *(const bf16x8*)(Bhi + boff1);
    bf16x8 vbl0 = *(const bf16x8*)(Blo + boff0);
    bf16x8 vbl1 = *(const bf16x8*)(Blo + boff1);
    *(bf16x8*)&sAhi[s0 * 8] = vah0;
    *(bf16x8*)&sAhi[s1 * 8] = vah1;
    *(bf16x8*)&sAlo[s0 * 8] = val0;
    *(bf16x8*)&sAlo[s1 * 8] = val1;
    *(bf16x8*)&sBhi[s0 * 8] = vbh0;
    *(bf16x8*)&sBhi[s1 * 8] = vbh1;
    *(bf16x8*)&sBlo[s0 * 8] = vbl0;
    *(bf16x8*)&sBlo[s1 * 8] = vbl1;
    __syncthreads();

    bf16x8 bh[4], bl[4];
#pragma unroll
    for (int tn = 0; tn < 4; ++tn) {
      const int nl = wn * 64 + tn * 16 + m16;
      bh[tn] = *(const bf16x8*)&sBhi[(q * 128 + nl) * 8];
      bl[tn] = *(const bf16x8*)&sBlo[(q * 128 + nl) * 8];
    }
#pragma unroll
    for (int tm = 0; tm < 4; ++tm) {
      const int ml = wm * 64 + tm * 16 + m16;
      bf16x8 ah = *(const bf16x8*)&sAhi[(q * 128 + ml) * 8];
      bf16x8 al = *(const bf16x8*)&sAlo[(q * 128 + ml) * 8];
#pragma unroll
      for (int tn = 0; tn < 4; ++tn) {
        acc[tm][tn] = __builtin_amdgcn_mfma_f32_16x16x32_bf16(ah, bh[tn], acc[tm][tn], 0, 0, 0);
        acc[tm][tn] = __builtin_amdgcn_mfma_f32_16x16x32_bf16(al, bh[tn], acc[tm][tn], 0, 0, 0);
        acc[tm][tn] = __builtin_amdgcn_mfma_f32_16x16x32_bf16(ah, bl[tn], acc[tm][tn], 0, 0, 0);
      }
    }
    __syncthreads();
    aoff0 += 32; aoff1 += 32; boff0 += 32; boff1 += 32;
  }

  const int kq = ncol0 >> 10;
  float rowsum[16];
#pragma unroll
  for (int i = 0; i < 16; ++i) rowsum[i] = 0.f;
#pragma unroll
  for (int tm = 0; tm < 4; ++tm) {
#pragma unroll
    for (int tn = 0; tn < 4; ++tn) {
      const int n = ncol0 + wn * 64 + tn * 16 + m16;
      const int h = n & (NH - 1);
      const float v4 = V4[kq * NH + h];
      const float bcv = bc[kq * NH + h];
#pragma unroll
      for (int j = 0; j < 4; ++j) {
        const int R = row0 + wm * 64 + tm * 16 + q * 4 + j;
        const int b = R / NL;
        float val = acc[tm][tn][j] + inp[(size_t)b * NH + h] + bcv;
        rowsum[tm * 4 + j] += v4 * tanhf(val);
      }
    }
  }
#pragma unroll
  for (int tm = 0; tm < 4; ++tm)
#pragma unroll
    for (int j = 0; j < 4; ++j)
      red[wm * 64 + tm * 16 + q * 4 + j][wn * 16 + m16] = rowsum[tm * 4 + j];
  __syncthreads();
  if (tid < 128) {
    float ssum = 0.f;
#pragma unroll
    for (int x = 0; x < 32; ++x) ssum += red[tid][x];
    const int R = row0 + tid;
    const int b = R / NL, l = R - b * NL;
    atomicAdd(&att[b * 28 + kq * NL + l], ssum);
  }
}

// ---------------- elementwise: query chain ----------------
__global__ __launch_bounds__(256) void k_query(
    const float* __restrict__ edge4, const float* __restrict__ st,
    const float* __restrict__ lin, float* __restrict__ query) {
  const size_t i = (size_t)blockIdx.x * 256 + threadIdx.x;
  float e4 = edge4[i];
  float qt = fmaxf(e4 + st[i], 0.f);
  float l = lin[i];
  float q = fmaxf(qt + l, 0.f);
  q = fmaxf(q + l, 0.f);
  query[i] = q;
}

// ---------------- att finish: mask -> -inf -> 10*tanh ----------------
__global__ __launch_bounds__(256) void k_finish(
    float* __restrict__ att, const int* __restrict__ mask) {
  const int i = blockIdx.x * 256 + threadIdx.x;
  const int b = i / 28;
  const int j = i - b * 28;
  const int l = j % NL;
  float v = att[i];
  att[i] = (mask[b * NL + l] != 0) ? (10.f * tanhf(v)) : -10.f;
}

// ---------------- per-column (over B) softmax stats ----------------
__global__ __launch_bounds__(256) void k_colstats(
    const float* __restrict__ att, float* __restrict__ Mv, float* __restrict__ Sv) {
  const int j = blockIdx.x;
  const int tid = threadIdx.x;
  __shared__ float sm[256];
  float m = -INFINITY;
  for (int b = tid; b < NB; b += 256) m = fmaxf(m, att[b * 28 + j]);
  sm[tid] = m;
  __syncthreads();
  for (int s = 128; s > 0; s >>= 1) {
    if (tid < s) sm[tid] = fmaxf(sm[tid], sm[tid + s]);
    __syncthreads();
  }
  const float M = sm[0];
  __syncthreads();
  float sum = 0.f;
  for (int b = tid; b < NB; b += 256) sum += expf(att[b * 28 + j] - M);
  sm[tid] = sum;
  __syncthreads();
  for (int s = 128; s > 0; s >>= 1) {
    if (tid < s) sm[tid] += sm[tid + s];
    __syncthreads();
  }
  if (tid == 0) { Mv[j] = M; Sv[j] = sm[0]; }
}

// ---------------- sampling + close-call compaction ----------------
__global__ __launch_bounds__(256) void k_sample(
    const float* __restrict__ att, const float* __restrict__ Mv,
    const float* __restrict__ Sv, const int* __restrict__ mask,
    float* __restrict__ out, int* __restrict__ flag,
    int* __restrict__ cnt, int* __restrict__ list) {
  const int b = blockIdx.x * 256 + threadIdx.x;
  if (b >= NB) return;
  float best = -INFINITY, second = -INFINITY;
  int bj = 0;
  for (int j = 0; j < 28; ++j) {
    float y = (att[b * 28 + j] - Mv[j]) - logf(Sv[j]) + gumbel_for(b, j);
    if (y > best) { second = best; best = y; bj = j; }
    else if (y > second) second = y;
  }
  out[b] = (float)bj;
  out[NB + b] = expf(att[b * 28 + bj] - Mv[bj]) / Sv[bj];
  const int* mrow = mask + b * NL;
#pragma unroll
  for (int l = 0; l < NL; ++l)
    out[2 * NB + (size_t)b * NL + l] = (float)(mrow[l] - ((l == bj) ? 1 : 0));
  const int f = (best - second < GAP) ? 1 : 0;
  flag[b] = f;
  if (f) {
    int pos = atomicAdd(cnt, 1);
    list[pos] = b;
  }
}

// ---------------- fp32 inp recompute for flagged rows ----------------
// Recomputes edge(t=0..4), st, qt, query, inp fully in fp32 for each
// flagged row b, overwriting inp[b,:] in place.
__global__ __launch_bounds__(256) void k_fixup_inp(
    const int* __restrict__ cnt, const int* __restrict__ list,
    const int* __restrict__ xes, const float* __restrict__ enc,
    const float* __restrict__ Wh, const float* __restrict__ Wv,
    const float* __restrict__ Wsh, const float* __restrict__ Wsv,
    const float* __restrict__ We, const float* __restrict__ Wq,
    const float* __restrict__ bq, const float* __restrict__ lin,
    float* __restrict__ inp) {
  __shared__ float sE[NSTEP][ND];
  __shared__ float sRow[2][ND];
  __shared__ float sQ[ND];
  const int tid = threadIdx.x;
  const int n = cnt[0];
  for (int it = blockIdx.x; it < n; it += gridDim.x) {
    const int b = list[it];
    for (int t = 0; t < NSTEP; ++t) {
      const int hidx = xes[(b * NT + t) * 3 + 0];
      const int vidx = xes[(b * NT + t) * 3 + 1];
      const int tt   = xes[(b * NT + t) * 3 + 2];
      *(float4*)&sRow[0][tid * 4] = *(const float4*)(enc + (((size_t)b * NL + hidx) << 10) + tid * 4);
      *(float4*)&sRow[1][tid * 4] = *(const float4*)(enc + (((size_t)b * NL + vidx) << 10) + tid * 4);
      __syncthreads();
      const float* W0 = (tt == 0) ? Wh : Wsh;
      const float* W1 = (tt == 0) ? Wv : Wsv;
#pragma unroll
      for (int p = 0; p < 4; ++p) {
        const int nn = tid + 256 * p;
        const float* w0 = W0 + ((size_t)nn << 10);
        const float* w1 = W1 + ((size_t)nn << 10);
        float d = 0.f;
        for (int k = 0; k < ND; k += 4) {
          float4 a = *(const float4*)(w0 + k);
          float4 c = *(const float4*)(w1 + k);
          float4 e0 = *(const float4*)&sRow[0][k];
          float4 e1 = *(const float4*)&sRow[1][k];
          d += a.x * e0.x + a.y * e0.y + a.z * e0.z + a.w * e0.w;
          d += c.x * e1.x + c.y * e1.y + c.z * e1.z + c.w * e1.w;
        }
        sE[t][nn] = d;
      }
      __syncthreads();
    }
    // st = max(0, max_t sE[t] @ We^T); query chain; stash in sQ
#pragma unroll
    for (int p = 0; p < 4; ++p) {
      const int nn = tid + 256 * p;
      const float* w = We + ((size_t)nn << 10);
      float stv = 0.f;
      for (int t = 0; t < NSTEP; ++t) {
        float d = 0.f;
        for (int k = 0; k < ND; k += 4) {
          float4 a = *(const float4*)(w + k);
          float4 e = *(const float4*)&sE[t][k];
          d += a.x * e.x + a.y * e.y + a.z * e.z + a.w * e.w;
        }
        stv = fmaxf(stv, d);
      }
      float qt = fmaxf(sE[4][nn] + stv, 0.f);
      float lb = lin[(size_t)b * NH + nn];
      float qv = fmaxf(fmaxf(qt + lb, 0.f) + lb, 0.f);
      sQ[nn] = qv;
    }
    __syncthreads();
#pragma unroll
    for (int p = 0; p < 4; ++p) {
      const int nn = tid + 256 * p;
      const float* w = Wq + ((size_t)nn << 10);
      float d = 0.f;
      for (int k = 0; k < ND; k += 4) {
        float4 a = *(const float4*)(w + k);
        float4 e = *(const float4*)&sQ[k];
        d += a.x * e.x + a.y * e.y + a.z * e.z + a.w * e.w;
      }
      inp[(size_t)b * NH + nn] = d + bq[nn];
    }
    __syncthreads();
  }
}

// ---------------- fp32 att recompute for flagged rows ----------------
__global__ __launch_bounds__(256) void k_fixup_att(
    const int* __restrict__ cnt, const int* __restrict__ list,
    const float* __restrict__ enc, const float* __restrict__ Wc,
    const float* __restrict__ bc, const float* __restrict__ V4,
    const float* __restrict__ inp, const int* __restrict__ mask,
    float* __restrict__ att) {
  const int kq = blockIdx.x;
  const int tid = threadIdx.x;
  __shared__ float sEnc[NL][ND];
  __shared__ float sm[256];
  const int n = cnt[0];
  for (int it = blockIdx.y; it < n; it += gridDim.y) {
    const int b = list[it];
    for (int i = tid; i < NL * 256; i += 256) {
      const int l = i >> 8, c = (i & 255) * 4;
      *(float4*)&sEnc[l][c] = *(const float4*)(enc + (((size_t)b * NL + l) << 10) + c);
    }
    __syncthreads();
    float accl[NL];
#pragma unroll
    for (int l = 0; l < NL; ++l) accl[l] = 0.f;
    for (int hp = 0; hp < 2; ++hp) {
      const int h0 = tid + hp * 512;
      const int h1 = h0 + 256;
      const float* w0 = Wc + (((size_t)kq * NH + h0) << 10);
      const float* w1 = Wc + (((size_t)kq * NH + h1) << 10);
      float d0[NL], d1[NL];
#pragma unroll
      for (int l = 0; l < NL; ++l) { d0[l] = 0.f; d1[l] = 0.f; }
      for (int k = 0; k < ND; k += 4) {
        float4 a = *(const float4*)(w0 + k);
        float4 c = *(const float4*)(w1 + k);
#pragma unroll
        for (int l = 0; l < NL; ++l) {
          float4 e = *(const float4*)&sEnc[l][k];
          d0[l] += a.x * e.x + a.y * e.y + a.z * e.z + a.w * e.w;
          d1[l] += c.x * e.x + c.y * e.y + c.z * e.z + c.w * e.w;
        }
      }
      const float i0 = inp[(size_t)b * NH + h0], i1 = inp[(size_t)b * NH + h1];
      const float b0 = bc[kq * NH + h0], b1 = bc[kq * NH + h1];
      const float v0 = V4[kq * NH + h0], v1 = V4[kq * NH + h1];
#pragma unroll
      for (int l = 0; l < NL; ++l)
        accl[l] += v0 * tanhf(d0[l] + i0 + b0) + v1 * tanhf(d1[l] + i1 + b1);
    }
    for (int l = 0; l < NL; ++l) {
      sm[tid] = accl[l];
      __syncthreads();
      for (int s = 128; s > 0; s >>= 1) {
        if (tid < s) sm[tid] += sm[tid + s];
        __syncthreads();
      }
      if (tid == 0) {
        float a = (mask[b * NL + l] != 0) ? (10.f * tanhf(sm[0])) : -10.f;
        att[b * 28 + kq * NL + l] = a;
      }
      __syncthreads();
    }
    __syncthreads();
  }
}

// ---------------- re-sample flagged rows with fixed att ----------------
__global__ __launch_bounds__(256) void k_resample(
    const int* __restrict__ flag, const float* __restrict__ att,
    const float* __restrict__ Mv, const float* __restrict__ Sv,
    const int* __restrict__ mask, float* __restrict__ out) {
  const int b = blockIdx.x * 256 + threadIdx.x;
  if (b >= NB) return;
  if (!flag[b]) return;
  float best = -INFINITY;
  int bj = 0;
  for (int j = 0; j < 28; ++j) {
    float y = (att[b * 28 + j] - Mv[j]) - logf(Sv[j]) + gumbel_for(b, j);
    if (y > best) { best = y; bj = j; }
  }
  out[b] = (float)bj;
  out[NB + b] = expf(att[b * 28 + bj] - Mv[bj]) / Sv[bj];
  const int* mrow = mask + b * NL;
#pragma unroll
  for (int l = 0; l < NL; ++l)
    out[2 * NB + (size_t)b * NL + l] = (float)(mrow[l] - ((l == bj) ? 1 : 0));
}

extern "C" void kernel_launch(void* const* d_in, const int* in_sizes, int n_in,
                              void* d_out, int out_size, void* d_ws, size_t ws_size,
                              hipStream_t stream) {
  const float* enc  = (const float*)d_in[0];
  const int*   xes  = (const int*)d_in[1];
  const int*   idx  = (const int*)d_in[2];
  const int*   mask = (const int*)d_in[3];
  const float* Wq   = (const float*)d_in[4];
  const float* bq   = (const float*)d_in[5];
  const float* Wc   = (const float*)d_in[6];
  const float* bc   = (const float*)d_in[7];
  const float* V4   = (const float*)d_in[8];
  const float* Wi   = (const float*)d_in[9];
  const float* bi   = (const float*)d_in[10];
  const float* Wh   = (const float*)d_in[11];
  const float* Wv   = (const float*)d_in[12];
  const float* Wsh  = (const float*)d_in[13];
  const float* Wsv  = (const float*)d_in[14];
  const float* We   = (const float*)d_in[15];
  (void)in_sizes; (void)n_in; (void)out_size; (void)ws_size;

  // ---- workspace layout (~324 MB) ----
  char* p = (char*)d_ws;
  float* edge4 = (float*)p;                 p += (size_t)NB * NH * 4;           // 16.8 MB
  unsigned* ehilo = (unsigned*)p;           p += (size_t)NSTEP * NB * NH * 4;   // 83.9 MB
  float* st = (float*)p;                    p += (size_t)NB * NH * 4;
  float* lin = (float*)p;                   p += (size_t)NB * NH * 4;
  float* query = (float*)p;                 p += (size_t)NB * NH * 4;
  float* inp = (float*)p;                   p += (size_t)NB * NH * 4;           // 67.1 MB total
  float* att = (float*)p;                   p += (size_t)NB * 28 * 4;
  float* Mv = (float*)p;                    p += 28 * 4;
  float* Sv = (float*)p;                    p += 28 * 4;
  int* flag = (int*)p;                      p += NB * 4;
  int* cnt = (int*)p;                       p += 4 * 4;
  int* list = (int*)p;                      p += NB * 4;
  int* cls_cnt = (int*)p;                   p += 2 * 4;
  int* l0 = (int*)p;                        p += NSTEP * NB * 4;
  int* l1 = (int*)p;                        p += NSTEP * NB * 4;
  unsigned short* enc_hi = (unsigned short*)p; p += (size_t)NB * NL * ND * 2;   // 58.7 MB
  unsigned short* enc_lo = (unsigned short*)p; p += (size_t)NB * NL * ND * 2;
  unsigned short* w4hi = (unsigned short*)p;   p += (size_t)4 * NH * ND * 2;    // 8.4 MB
  unsigned short* w4lo = (unsigned short*)p;   p += (size_t)4 * NH * ND * 2;
  unsigned short* wehi = (unsigned short*)p;   p += (size_t)NH * ND * 2;
  unsigned short* welo = (unsigned short*)p;   p += (size_t)NH * ND * 2;
  unsigned short* wc_hi = (unsigned short*)p;  p += (size_t)4 * NH * ND * 2;
  unsigned short* wc_lo = (unsigned short*)p;  p += (size_t)4 * NH * ND * 2;
  float* out = (float*)d_out;

  hipMemsetAsync(st, 0, (size_t)NB * NH * sizeof(float), stream);
  hipMemsetAsync(att, 0, (size_t)NB * 28 * sizeof(float), stream);
  hipMemsetAsync(cnt, 0, sizeof(int), stream);
  hipMemsetAsync(cls_cnt, 0, 2 * sizeof(int), stream);

  dim3 blk(256);
  // bf16 hi/lo planes
  k_split<<<dim3((NB * NL * ND) / 1024), blk, 0, stream>>>(enc, enc_hi, enc_lo);
  k_split<<<dim3((4 * NH * ND) / 1024), blk, 0, stream>>>(Wc, wc_hi, wc_lo);
  k_split<<<dim3((NH * ND) / 1024), blk, 0, stream>>>(Wh, w4hi, w4lo);
  k_split<<<dim3((NH * ND) / 1024), blk, 0, stream>>>(Wv, w4hi + (size_t)NH * ND, w4lo + (size_t)NH * ND);
  k_split<<<dim3((NH * ND) / 1024), blk, 0, stream>>>(Wsh, w4hi + (size_t)2 * NH * ND, w4lo + (size_t)2 * NH * ND);
  k_split<<<dim3((NH * ND) / 1024), blk, 0, stream>>>(Wsv, w4hi + (size_t)3 * NH * ND, w4lo + (size_t)3 * NH * ND);
  k_split<<<dim3((NH * ND) / 1024), blk, 0, stream>>>(We, wehi, welo);
  // classify rows by tt
  k_classify<<<dim3((NSTEP * NB) / 256), blk, 0, stream>>>(xes, cls_cnt, l0, l1);
  // edges via MFMA (K=2048, two classes, compacted)
  g1_mfma<<<dim3(162, 8), blk, 0, stream>>>(cls_cnt, l0, l1, xes, enc_hi, enc_lo,
                                            w4hi, w4lo, ehilo, edge4);
  // lin = gather(enc, idx) @ Wi^T + bi  (fp32)
  gemm_bias<<<dim3(16, 64), blk, 0, stream>>>(nullptr, idx, enc, Wi, bi, lin);
  // st = max(0, max_t edge@We^T) via MFMA
  g2_mfma<<<dim3(160, 8), blk, 0, stream>>>(ehilo, wehi, welo, (unsigned*)st);
  // query
  k_query<<<dim3((NB * NH) / 256), blk, 0, stream>>>(edge4, st, lin, query);
  // inp = query @ Wq^T + bq (fp32)
  gemm_bias<<<dim3(16, 64), blk, 0, stream>>>(query, nullptr, enc, Wq, bq, inp);
  // att partial sums via bf16 MFMA (3-term hi/lo)
  g5_mfma<<<dim3(224, 32), blk, 0, stream>>>(enc_hi, enc_lo, wc_hi, wc_lo,
                                             inp, bc, V4, att);
  k_finish<<<dim3((NB * 28) / 256), blk, 0, stream>>>(att, mask);
  k_colstats<<<dim3(28), blk, 0, stream>>>(att, Mv, Sv);
  k_sample<<<dim3(NB / 256), blk, 0, stream>>>(att, Mv, Sv, mask, out, flag, cnt, list);
  // fp32 fixup chain for flagged rows: inp, then att, then resample
  k_fixup_inp<<<dim3(64), blk, 0, stream>>>(cnt, list, xes, enc, Wh, Wv, Wsh, Wsv,
                                            We, Wq, bq, lin, inp);
  k_fixup_att<<<dim3(4, 64), blk, 0, stream>>>(cnt, list, enc, Wc, bc, V4, inp, mask, att);
  k_resample<<<dim3(NB / 256), blk, 0, stream>>>(flag, att, Mv, Sv, mask, out);
}

// Round 5
// 3442.294 us; speedup vs baseline: 2.1965x; 2.1965x over previous
//
#include <hip/hip_runtime.h>

// Problem dims (fixed)
#define NB 4096   // B
#define NL 7      // L
#define ND 1024   // D
#define NH 1024   // H
#define NT 6      // T
#define NSTEP 5   // effective scan steps (t = 0..4)
#define GAP 0.02f // gumbel top-2 gap below which we recompute the row in fp32
#define MAXF 1024 // max flagged rows handled by the fp32 fixup chain (~10x margin)

typedef __attribute__((ext_vector_type(8))) short bf16x8;
typedef __attribute__((ext_vector_type(4))) float f32x4;

// ---------------- threefry2x32 (JAX-compatible, 20 rounds) ----------------
__device__ __forceinline__ unsigned rotl32(unsigned x, int r) {
  return (x << r) | (x >> (32 - r));
}

__device__ __forceinline__ void threefry2x32(unsigned k0, unsigned k1,
                                             unsigned x0, unsigned x1,
                                             unsigned& o0, unsigned& o1) {
  unsigned ks2 = k0 ^ k1 ^ 0x1BD11BDAu;
#define TFR(R) { x0 += x1; x1 = rotl32(x1, (R)); x1 ^= x0; }
  x0 += k0; x1 += k1;
  TFR(13) TFR(15) TFR(26) TFR(6)
  x0 += k1; x1 += ks2 + 1u;
  TFR(17) TFR(29) TFR(16) TFR(24)
  x0 += ks2; x1 += k0 + 2u;
  TFR(13) TFR(15) TFR(26) TFR(6)
  x0 += k0; x1 += k1 + 3u;
  TFR(17) TFR(29) TFR(16) TFR(24)
  x0 += k1; x1 += ks2 + 4u;
  TFR(13) TFR(15) TFR(26) TFR(6)
  x0 += ks2; x1 += k0 + 5u;
#undef TFR
  o0 = x0; o1 = x1;
}

__device__ __forceinline__ float gumbel_for(int b, int j) {
  unsigned o0, o1;
  threefry2x32(0u, 42u, 0u, (unsigned)(b * 28 + j), o0, o1);
  unsigned bits = o0 ^ o1;
  const float TINY = 1.17549435e-38f;
  float u = __uint_as_float((bits >> 9) | 0x3f800000u) - 1.0f;
  u = fmaxf(TINY, u + TINY);
  return -logf(-logf(u));
}

// ---------------- bf16 hi/lo split ----------------
__device__ __forceinline__ unsigned short f2bf(float f) {
  unsigned u = __float_as_uint(f);
  unsigned r = u + 0x7FFFu + ((u >> 16) & 1u);
  return (unsigned short)(r >> 16);
}
__device__ __forceinline__ float bf2f(unsigned short h) {
  return __uint_as_float(((unsigned)h) << 16);
}

__global__ __launch_bounds__(256) void k_split(
    const float* __restrict__ x, unsigned short* __restrict__ hi,
    unsigned short* __restrict__ lo) {
  const size_t i = ((size_t)blockIdx.x * 256 + threadIdx.x) * 4;
  float4 v = *(const float4*)(x + i);
  ushort4 h, l;
  h.x = f2bf(v.x); l.x = f2bf(v.x - bf2f(h.x));
  h.y = f2bf(v.y); l.y = f2bf(v.y - bf2f(h.y));
  h.z = f2bf(v.z); l.z = f2bf(v.z - bf2f(h.z));
  h.w = f2bf(v.w); l.w = f2bf(v.w - bf2f(h.w));
  *(ushort4*)(hi + i) = h;
  *(ushort4*)(lo + i) = l;
}

// ---------------- shared 64x64 fp32 tile core ------
__device__ __forceinline__ void tile_compute(const float (*As)[68],
                                             const float (*Bs)[68],
                                             float acc[4][4], int tx, int ty) {
#pragma unroll
  for (int kk = 0; kk < 16; ++kk) {
    float4 a  = *(const float4*)&As[kk][ty * 4];
    float4 bb = *(const float4*)&Bs[kk][tx * 4];
    acc[0][0] += a.x * bb.x; acc[0][1] += a.x * bb.y; acc[0][2] += a.x * bb.z; acc[0][3] += a.x * bb.w;
    acc[1][0] += a.y * bb.x; acc[1][1] += a.y * bb.y; acc[1][2] += a.y * bb.z; acc[1][3] += a.y * bb.w;
    acc[2][0] += a.z * bb.x; acc[2][1] += a.z * bb.y; acc[2][2] += a.z * bb.z; acc[2][3] += a.z * bb.w;
    acc[3][0] += a.w * bb.x; acc[3][1] += a.w * bb.y; acc[3][2] += a.w * bb.z; acc[3][3] += a.w * bb.w;
  }
}

#define TILE_DECLS \
  __shared__ float As[16][68]; \
  __shared__ float Bs[16][68]; \
  float acc[4][4] = {}; \
  const int tid = threadIdx.x; \
  const int tx = tid & 15, ty = tid >> 4; \
  const int row0 = blockIdx.y * 64, col0 = blockIdx.x * 64; \
  const int lm = tid >> 2; \
  const int lk4 = (tid & 3) * 4;

#define STORE_AS(av) { As[lk4+0][lm]=(av).x; As[lk4+1][lm]=(av).y; As[lk4+2][lm]=(av).z; As[lk4+3][lm]=(av).w; }
#define STORE_BS(bv) { Bs[lk4+0][lm]=(bv).x; Bs[lk4+1][lm]=(bv).y; Bs[lk4+2][lm]=(bv).z; Bs[lk4+3][lm]=(bv).w; }

// ---------------- C = A @ Bw^T + bias (A optionally gathered) -- fp32 -----
__global__ __launch_bounds__(256) void gemm_bias(
    const float* __restrict__ A, const int* __restrict__ gidx,
    const float* __restrict__ enc, const float* __restrict__ Bw,
    const float* __restrict__ bias, float* __restrict__ C) {
  TILE_DECLS
  const int r = row0 + lm;
  const float* arow = gidx ? (enc + (((size_t)r * NL + gidx[r]) << 10))
                           : (A + ((size_t)r << 10));
  const float* brow = Bw + ((size_t)(col0 + lm) << 10);
  for (int k0 = 0; k0 < ND; k0 += 16) {
    float4 av = *(const float4*)(arow + k0 + lk4);
    STORE_AS(av)
    float4 bv = *(const float4*)(brow + k0 + lk4);
    STORE_BS(bv)
    __syncthreads();
    tile_compute(As, Bs, acc, tx, ty);
    __syncthreads();
  }
#pragma unroll
  for (int i = 0; i < 4; ++i) {
    const int rr = row0 + ty * 4 + i;
    const int n0 = col0 + tx * 4;
    float4 v = make_float4(acc[i][0] + bias[n0 + 0], acc[i][1] + bias[n0 + 1],
                           acc[i][2] + bias[n0 + 2], acc[i][3] + bias[n0 + 3]);
    *(float4*)(C + ((size_t)rr << 10) + n0) = v;
  }
}

// ---------------- classify rows (t,b) by tt ----------------
__global__ __launch_bounds__(256) void k_classify(
    const int* __restrict__ xes, int* __restrict__ cls_cnt,
    int* __restrict__ l0, int* __restrict__ l1) {
  const int r = blockIdx.x * 256 + threadIdx.x;
  if (r >= NSTEP * NB) return;
  const int b = r & (NB - 1), t = r >> 12;
  const int tt = xes[(b * NT + t) * 3 + 2];
  if (tt == 0) { int p = atomicAdd(&cls_cnt[0], 1); l0[p] = r; }
  else         { int p = atomicAdd(&cls_cnt[1], 1); l1[p] = r; }
}

// ---------------- G1 (bf16 MFMA): edges, K=2048 per class ----------------
__global__ __launch_bounds__(256) void g1_mfma(
    const int* __restrict__ cls_cnt, const int* __restrict__ l0,
    const int* __restrict__ l1, const int* __restrict__ xes,
    const unsigned short* __restrict__ enc_hi, const unsigned short* __restrict__ enc_lo,
    const unsigned short* __restrict__ w4hi, const unsigned short* __restrict__ w4lo,
    unsigned* __restrict__ ehilo, float* __restrict__ edge4) {
  const int n0c = cls_cnt[0], n1c = cls_cnt[1];
  const int tiles0 = (n0c + 127) >> 7, tiles1 = (n1c + 127) >> 7;
  const int bx = blockIdx.x;
  if (bx >= tiles0 + tiles1) return;
  int cls, mtile, nc;
  const int* list;
  if (bx < tiles0) { cls = 0; mtile = bx; nc = n0c; list = l0; }
  else { cls = 1; mtile = bx - tiles0; nc = n1c; list = l1; }

  __shared__ unsigned short sAhi[4096], sAlo[4096], sBhi[4096], sBlo[4096];
  const int tid = threadIdx.x;
  const int ncol0 = blockIdx.y * 128;

  const int ri = tid & 127;
  const int c0 = tid >> 7;
  const int c1 = c0 + 2;
  const int li = mtile * 128 + ri;
  const int rsrc = list[(li < nc) ? li : (nc - 1)];
  const int b = rsrc & (NB - 1), t = rsrc >> 12;
  const int hidx = xes[(b * NT + t) * 3 + 0];
  const int vidx = xes[(b * NT + t) * 3 + 1];
  const unsigned short* ha = enc_hi + (((size_t)b * NL + hidx) << 10);
  const unsigned short* la = enc_lo + (((size_t)b * NL + hidx) << 10);
  const unsigned short* hb = enc_hi + (((size_t)b * NL + vidx) << 10);
  const unsigned short* lb = enc_lo + (((size_t)b * NL + vidx) << 10);
  const size_t wrow = ((size_t)(ncol0 + ri)) << 10;

  const int wave = tid >> 6, lane = tid & 63;
  const int wm = wave >> 1, wn = wave & 1;
  const int q = lane >> 4, m16 = lane & 15;

  f32x4 acc[4][4] = {};

  for (int kt = 0; kt < 64; ++kt) {
    const int seg = (kt < 32) ? (cls * 2) : (cls * 2 + 1);
    const int kl = (kt & 31) * 32;
    const unsigned short* ah = (kt < 32) ? ha : hb;
    const unsigned short* al = (kt < 32) ? la : lb;
    bf16x8 vah0 = *(const bf16x8*)(ah + kl + c0 * 8);
    bf16x8 vah1 = *(const bf16x8*)(ah + kl + c1 * 8);
    bf16x8 val0 = *(const bf16x8*)(al + kl + c0 * 8);
    bf16x8 val1 = *(const bf16x8*)(al + kl + c1 * 8);
    const unsigned short* wh = w4hi + (((size_t)seg) << 20) + wrow + kl;
    const unsigned short* wl = w4lo + (((size_t)seg) << 20) + wrow + kl;
    bf16x8 vbh0 = *(const bf16x8*)(wh + c0 * 8);
    bf16x8 vbh1 = *(const bf16x8*)(wh + c1 * 8);
    bf16x8 vbl0 = *(const bf16x8*)(wl + c0 * 8);
    bf16x8 vbl1 = *(const bf16x8*)(wl + c1 * 8);
    *(bf16x8*)&sAhi[(c0 * 128 + ri) * 8] = vah0;
    *(bf16x8*)&sAhi[(c1 * 128 + ri) * 8] = vah1;
    *(bf16x8*)&sAlo[(c0 * 128 + ri) * 8] = val0;
    *(bf16x8*)&sAlo[(c1 * 128 + ri) * 8] = val1;
    *(bf16x8*)&sBhi[(c0 * 128 + ri) * 8] = vbh0;
    *(bf16x8*)&sBhi[(c1 * 128 + ri) * 8] = vbh1;
    *(bf16x8*)&sBlo[(c0 * 128 + ri) * 8] = vbl0;
    *(bf16x8*)&sBlo[(c1 * 128 + ri) * 8] = vbl1;
    __syncthreads();

    bf16x8 bh[4], bl[4];
#pragma unroll
    for (int tn = 0; tn < 4; ++tn) {
      const int nl = wn * 64 + tn * 16 + m16;
      bh[tn] = *(const bf16x8*)&sBhi[(q * 128 + nl) * 8];
      bl[tn] = *(const bf16x8*)&sBlo[(q * 128 + nl) * 8];
    }
#pragma unroll
    for (int tm = 0; tm < 4; ++tm) {
      const int ml = wm * 64 + tm * 16 + m16;
      bf16x8 ah8 = *(const bf16x8*)&sAhi[(q * 128 + ml) * 8];
      bf16x8 al8 = *(const bf16x8*)&sAlo[(q * 128 + ml) * 8];
#pragma unroll
      for (int tn = 0; tn < 4; ++tn) {
        acc[tm][tn] = __builtin_amdgcn_mfma_f32_16x16x32_bf16(ah8, bh[tn], acc[tm][tn], 0, 0, 0);
        acc[tm][tn] = __builtin_amdgcn_mfma_f32_16x16x32_bf16(al8, bh[tn], acc[tm][tn], 0, 0, 0);
        acc[tm][tn] = __builtin_amdgcn_mfma_f32_16x16x32_bf16(ah8, bl[tn], acc[tm][tn], 0, 0, 0);
      }
    }
    __syncthreads();
  }

#pragma unroll
  for (int tm = 0; tm < 4; ++tm) {
#pragma unroll
    for (int j = 0; j < 4; ++j) {
      const int rl = wm * 64 + tm * 16 + q * 4 + j;
      const int li2 = mtile * 128 + rl;
      if (li2 < nc) {
        const int rr = list[li2];
#pragma unroll
        for (int tn = 0; tn < 4; ++tn) {
          const int n = ncol0 + wn * 64 + tn * 16 + m16;
          const float val = acc[tm][tn][j];
          unsigned short h = f2bf(val);
          unsigned short l = f2bf(val - bf2f(h));
          ehilo[(size_t)rr * NH + n] = (unsigned)h | ((unsigned)l << 16);
          if (rr >= 4 * NB) edge4[(size_t)(rr - 4 * NB) * NH + n] = val;
        }
      }
    }
  }
}

// ---------------- G2 (bf16 MFMA): st = max(0, max_t edge@We^T) ------------
__global__ __launch_bounds__(256) void g2_mfma(
    const unsigned* __restrict__ ehilo,
    const unsigned short* __restrict__ wehi, const unsigned short* __restrict__ welo,
    unsigned* __restrict__ st) {
  __shared__ unsigned short sAhi[4096], sAlo[4096], sBhi[4096], sBlo[4096];
  const int tid = threadIdx.x;
  const int row0 = blockIdx.x * 128;
  const int ncol0 = blockIdx.y * 128;

  const int ri = tid & 127;
  const int c0 = tid >> 7;
  const int c1 = c0 + 2;
  const size_t arow = (size_t)(row0 + ri) * NH;
  const size_t wrow = ((size_t)(ncol0 + ri)) << 10;

  const int wave = tid >> 6, lane = tid & 63;
  const int wm = wave >> 1, wn = wave & 1;
  const int q = lane >> 4, m16 = lane & 15;

  f32x4 acc[4][4] = {};

  for (int kt = 0; kt < 32; ++kt) {
    const int kl = kt * 32;
    uint4 p00 = *(const uint4*)(ehilo + arow + kl + c0 * 8);
    uint4 p01 = *(const uint4*)(ehilo + arow + kl + c0 * 8 + 4);
    uint4 p10 = *(const uint4*)(ehilo + arow + kl + c1 * 8);
    uint4 p11 = *(const uint4*)(ehilo + arow + kl + c1 * 8 + 4);
    bf16x8 ah0, al0, ah1, al1;
    {
      unsigned u[8] = {p00.x, p00.y, p00.z, p00.w, p01.x, p01.y, p01.z, p01.w};
#pragma unroll
      for (int i = 0; i < 8; ++i) { ah0[i] = (short)(u[i] & 0xffff); al0[i] = (short)(u[i] >> 16); }
      unsigned v[8] = {p10.x, p10.y, p10.z, p10.w, p11.x, p11.y, p11.z, p11.w};
#pragma unroll
      for (int i = 0; i < 8; ++i) { ah1[i] = (short)(v[i] & 0xffff); al1[i] = (short)(v[i] >> 16); }
    }
    bf16x8 vbh0 = *(const bf16x8*)(wehi + wrow + kl + c0 * 8);
    bf16x8 vbh1 = *(const bf16x8*)(wehi + wrow + kl + c1 * 8);
    bf16x8 vbl0 = *(const bf16x8*)(welo + wrow + kl + c0 * 8);
    bf16x8 vbl1 = *(const bf16x8*)(welo + wrow + kl + c1 * 8);
    *(bf16x8*)&sAhi[(c0 * 128 + ri) * 8] = ah0;
    *(bf16x8*)&sAhi[(c1 * 128 + ri) * 8] = ah1;
    *(bf16x8*)&sAlo[(c0 * 128 + ri) * 8] = al0;
    *(bf16x8*)&sAlo[(c1 * 128 + ri) * 8] = al1;
    *(bf16x8*)&sBhi[(c0 * 128 + ri) * 8] = vbh0;
    *(bf16x8*)&sBhi[(c1 * 128 + ri) * 8] = vbh1;
    *(bf16x8*)&sBlo[(c0 * 128 + ri) * 8] = vbl0;
    *(bf16x8*)&sBlo[(c1 * 128 + ri) * 8] = vbl1;
    __syncthreads();

    bf16x8 bh[4], bl[4];
#pragma unroll
    for (int tn = 0; tn < 4; ++tn) {
      const int nl = wn * 64 + tn * 16 + m16;
      bh[tn] = *(const bf16x8*)&sBhi[(q * 128 + nl) * 8];
      bl[tn] = *(const bf16x8*)&sBlo[(q * 128 + nl) * 8];
    }
#pragma unroll
    for (int tm = 0; tm < 4; ++tm) {
      const int ml = wm * 64 + tm * 16 + m16;
      bf16x8 ah8 = *(const bf16x8*)&sAhi[(q * 128 + ml) * 8];
      bf16x8 al8 = *(const bf16x8*)&sAlo[(q * 128 + ml) * 8];
#pragma unroll
      for (int tn = 0; tn < 4; ++tn) {
        acc[tm][tn] = __builtin_amdgcn_mfma_f32_16x16x32_bf16(ah8, bh[tn], acc[tm][tn], 0, 0, 0);
        acc[tm][tn] = __builtin_amdgcn_mfma_f32_16x16x32_bf16(al8, bh[tn], acc[tm][tn], 0, 0, 0);
        acc[tm][tn] = __builtin_amdgcn_mfma_f32_16x16x32_bf16(ah8, bl[tn], acc[tm][tn], 0, 0, 0);
      }
    }
    __syncthreads();
  }

#pragma unroll
  for (int tm = 0; tm < 4; ++tm) {
#pragma unroll
    for (int j = 0; j < 4; ++j) {
      const int rr = row0 + wm * 64 + tm * 16 + q * 4 + j;
      const int b = rr & (NB - 1);
#pragma unroll
      for (int tn = 0; tn < 4; ++tn) {
        const int n = ncol0 + wn * 64 + tn * 16 + m16;
        unsigned val = __float_as_uint(fmaxf(acc[tm][tn][j], 0.f));
        atomicMax(&st[(size_t)b * NH + n], val);
      }
    }
  }
}

// ---------------- G5 (bf16 MFMA): fused ctx GEMM + tanh + V4 reduce --------
__global__ __launch_bounds__(256) void g5_mfma(
    const unsigned short* __restrict__ Ahi, const unsigned short* __restrict__ Alo,
    const unsigned short* __restrict__ Bhi, const unsigned short* __restrict__ Blo,
    const float* __restrict__ inp, const float* __restrict__ bc,
    const float* __restrict__ V4, float* __restrict__ att) {
  __shared__ unsigned short sAhi[4096], sAlo[4096], sBhi[4096], sBlo[4096];
  __shared__ float red[128][32];

  const int tid = threadIdx.x;
  const int row0 = blockIdx.x * 128;   // M-tile (224)
  const int ncol0 = blockIdx.y * 128;  // N-tile (32)

  const int s0 = tid, s1 = tid + 256;
  const int c0 = s0 >> 7, r0 = s0 & 127;
  const int c1 = s1 >> 7, r1 = s1 & 127;
  size_t aoff0 = (size_t)(row0 + r0) * ND + c0 * 8;
  size_t aoff1 = (size_t)(row0 + r1) * ND + c1 * 8;
  size_t boff0 = (size_t)(ncol0 + r0) * ND + c0 * 8;
  size_t boff1 = (size_t)(ncol0 + r1) * ND + c1 * 8;

  const int wave = tid >> 6, lane = tid & 63;
  const int wm = wave >> 1, wn = wave & 1;
  const int q = lane >> 4, m16 = lane & 15;

  f32x4 acc[4][4] = {};

  for (int kt = 0; kt < 32; ++kt) {
    bf16x8 vah0 = *(const bf16x8*)(Ahi + aoff0);
    bf16x8 vah1 = *(const bf16x8*)(Ahi + aoff1);
    bf16x8 val0 = *(const bf16x8*)(Alo + aoff0);
    bf16x8 val1 = *(const bf16x8*)(Alo + aoff1);
    bf16x8 vbh0 = *(const bf16x8*)(Bhi + boff0);
    bf16x8 vbh1 = *(const bf16x8*)(Bhi + boff1);
    bf16x8 vbl0 = *(const bf16x8*)(Blo + boff0);
    bf16x8 vbl1 = *(const bf16x8*)(Blo + boff1);
    *(bf16x8*)&sAhi[s0 * 8] = vah0;
    *(bf16x8*)&sAhi[s1 * 8] = vah1;
    *(bf16x8*)&sAlo[s0 * 8] = val0;
    *(bf16x8*)&sAlo[s1 * 8] = val1;
    *(bf16x8*)&sBhi[s0 * 8] = vbh0;
    *(bf16x8*)&sBhi[s1 * 8] = vbh1;
    *(bf16x8*)&sBlo[s0 * 8] = vbl0;
    *(bf16x8*)&sBlo[s1 * 8] = vbl1;
    __syncthreads();

    bf16x8 bh[4], bl[4];
#pragma unroll
    for (int tn = 0; tn < 4; ++tn) {
      const int nl = wn * 64 + tn * 16 + m16;
      bh[tn] = *(const bf16x8*)&sBhi[(q * 128 + nl) * 8];
      bl[tn] = *(const bf16x8*)&sBlo[(q * 128 + nl) * 8];
    }
#pragma unroll
    for (int tm = 0; tm < 4; ++tm) {
      const int ml = wm * 64 + tm * 16 + m16;
      bf16x8 ah = *(const bf16x8*)&sAhi[(q * 128 + ml) * 8];
      bf16x8 al = *(const bf16x8*)&sAlo[(q * 128 + ml) * 8];
#pragma unroll
      for (int tn = 0; tn < 4; ++tn) {
        acc[tm][tn] = __builtin_amdgcn_mfma_f32_16x16x32_bf16(ah, bh[tn], acc[tm][tn], 0, 0, 0);
        acc[tm][tn] = __builtin_amdgcn_mfma_f32_16x16x32_bf16(al, bh[tn], acc[tm][tn], 0, 0, 0);
        acc[tm][tn] = __builtin_amdgcn_mfma_f32_16x16x32_bf16(ah, bl[tn], acc[tm][tn], 0, 0, 0);
      }
    }
    __syncthreads();
    aoff0 += 32; aoff1 += 32; boff0 += 32; boff1 += 32;
  }

  const int kq = ncol0 >> 10;
  float rowsum[16];
#pragma unroll
  for (int i = 0; i < 16; ++i) rowsum[i] = 0.f;
#pragma unroll
  for (int tm = 0; tm < 4; ++tm) {
#pragma unroll
    for (int tn = 0; tn < 4; ++tn) {
      const int n = ncol0 + wn * 64 + tn * 16 + m16;
      const int h = n & (NH - 1);
      const float v4 = V4[kq * NH + h];
      const float bcv = bc[kq * NH + h];
#pragma unroll
      for (int j = 0; j < 4; ++j) {
        const int R = row0 + wm * 64 + tm * 16 + q * 4 + j;
        const int b = R / NL;
        float val = acc[tm][tn][j] + inp[(size_t)b * NH + h] + bcv;
        rowsum[tm * 4 + j] += v4 * tanhf(val);
      }
    }
  }
#pragma unroll
  for (int tm = 0; tm < 4; ++tm)
#pragma unroll
    for (int j = 0; j < 4; ++j)
      red[wm * 64 + tm * 16 + q * 4 + j][wn * 16 + m16] = rowsum[tm * 4 + j];
  __syncthreads();
  if (tid < 128) {
    float ssum = 0.f;
#pragma unroll
    for (int x = 0; x < 32; ++x) ssum += red[tid][x];
    const int R = row0 + tid;
    const int b = R / NL, l = R - b * NL;
    atomicAdd(&att[b * 28 + kq * NL + l], ssum);
  }
}

// ---------------- elementwise: query chain ----------------
__global__ __launch_bounds__(256) void k_query(
    const float* __restrict__ edge4, const float* __restrict__ st,
    const float* __restrict__ lin, float* __restrict__ query) {
  const size_t i = (size_t)blockIdx.x * 256 + threadIdx.x;
  float e4 = edge4[i];
  float qt = fmaxf(e4 + st[i], 0.f);
  float l = lin[i];
  float q = fmaxf(qt + l, 0.f);
  q = fmaxf(q + l, 0.f);
  query[i] = q;
}

// ---------------- att finish: mask -> -inf -> 10*tanh ----------------
__global__ __launch_bounds__(256) void k_finish(
    float* __restrict__ att, const int* __restrict__ mask) {
  const int i = blockIdx.x * 256 + threadIdx.x;
  const int b = i / 28;
  const int j = i - b * 28;
  const int l = j % NL;
  float v = att[i];
  att[i] = (mask[b * NL + l] != 0) ? (10.f * tanhf(v)) : -10.f;
}

// ---------------- per-column (over B) softmax stats ----------------
__global__ __launch_bounds__(256) void k_colstats(
    const float* __restrict__ att, float* __restrict__ Mv, float* __restrict__ Sv) {
  const int j = blockIdx.x;
  const int tid = threadIdx.x;
  __shared__ float sm[256];
  float m = -INFINITY;
  for (int b = tid; b < NB; b += 256) m = fmaxf(m, att[b * 28 + j]);
  sm[tid] = m;
  __syncthreads();
  for (int s = 128; s > 0; s >>= 1) {
    if (tid < s) sm[tid] = fmaxf(sm[tid], sm[tid + s]);
    __syncthreads();
  }
  const float M = sm[0];
  __syncthreads();
  float sum = 0.f;
  for (int b = tid; b < NB; b += 256) sum += expf(att[b * 28 + j] - M);
  sm[tid] = sum;
  __syncthreads();
  for (int s = 128; s > 0; s >>= 1) {
    if (tid < s) sm[tid] += sm[tid + s];
    __syncthreads();
  }
  if (tid == 0) { Mv[j] = M; Sv[j] = sm[0]; }
}

// ---------------- sampling + close-call compaction ----------------
__global__ __launch_bounds__(256) void k_sample(
    const float* __restrict__ att, const float* __restrict__ Mv,
    const float* __restrict__ Sv, const int* __restrict__ mask,
    float* __restrict__ out, int* __restrict__ flag,
    int* __restrict__ cnt, int* __restrict__ list) {
  const int b = blockIdx.x * 256 + threadIdx.x;
  if (b >= NB) return;
  float best = -INFINITY, second = -INFINITY;
  int bj = 0;
  for (int j = 0; j < 28; ++j) {
    float y = (att[b * 28 + j] - Mv[j]) - logf(Sv[j]) + gumbel_for(b, j);
    if (y > best) { second = best; best = y; bj = j; }
    else if (y > second) second = y;
  }
  out[b] = (float)bj;
  out[NB + b] = expf(att[b * 28 + bj] - Mv[bj]) / Sv[bj];
  const int* mrow = mask + b * NL;
#pragma unroll
  for (int l = 0; l < NL; ++l)
    out[2 * NB + (size_t)b * NL + l] = (float)(mrow[l] - ((l == bj) ? 1 : 0));
  const int f = (best - second < GAP) ? 1 : 0;
  flag[b] = f;
  if (f) {
    int pos = atomicAdd(cnt, 1);
    if (pos < MAXF) list[pos] = b;
  }
}

// ---------------- build per-class (it, t) lists for flagged rows ----------
__global__ __launch_bounds__(256) void k_build_fl(
    const int* __restrict__ cnt, const int* __restrict__ list,
    const int* __restrict__ xes, int* __restrict__ fl_cnt,
    int* __restrict__ fl0, int* __restrict__ fl1) {
  const int it = blockIdx.x * 256 + threadIdx.x;
  const int n = (cnt[0] < MAXF) ? cnt[0] : MAXF;
  if (it >= n) return;
  const int b = list[it];
#pragma unroll
  for (int t = 0; t < NSTEP; ++t) {
    const int tt = xes[(b * NT + t) * 3 + 2];
    const int e = it * 8 + t;
    if (tt == 0) { int p = atomicAdd(&fl_cnt[0], 1); fl0[p] = e; }
    else         { int p = atomicAdd(&fl_cnt[1], 1); fl1[p] = e; }
  }
}

// ---------------- fp32 fixup: edges for flagged (it,t) pairs ----------------
// edgeF[(it*5+t)*NH + n] = h@W0^T + v@W1^T  (K=2048 split in two halves)
__global__ __launch_bounds__(256) void k_fix_edge(
    const int* __restrict__ fl_cnt, const int* __restrict__ fl0,
    const int* __restrict__ fl1, const int* __restrict__ list,
    const int* __restrict__ xes, const float* __restrict__ enc,
    const float* __restrict__ Wh, const float* __restrict__ Wv,
    const float* __restrict__ Wsh, const float* __restrict__ Wsv,
    float* __restrict__ edgeF) {
  const int n0c = fl_cnt[0], n1c = fl_cnt[1];
  const int tiles0 = (n0c + 63) >> 6, tiles1 = (n1c + 63) >> 6;
  const int bx = blockIdx.x;
  if (bx >= tiles0 + tiles1) return;
  int cls, mtile, nc;
  const int* fl;
  if (bx < tiles0) { cls = 0; mtile = bx; nc = n0c; fl = fl0; }
  else { cls = 1; mtile = bx - tiles0; nc = n1c; fl = fl1; }

  __shared__ float As[16][68];
  __shared__ float Bs[16][68];
  float acc[4][4] = {};
  const int tid = threadIdx.x;
  const int tx = tid & 15, ty = tid >> 4;
  const int col0 = blockIdx.y * 64;
  const int lm = tid >> 2;
  const int lk4 = (tid & 3) * 4;

  const int li = mtile * 64 + lm;
  const int e = fl[(li < nc) ? li : (nc - 1)];
  const int it = e >> 3, t = e & 7;
  const int b = list[it];
  const int hidx = xes[(b * NT + t) * 3 + 0];
  const int vidx = xes[(b * NT + t) * 3 + 1];
  const float* arow0 = enc + (((size_t)b * NL + hidx) << 10);
  const float* arow1 = enc + (((size_t)b * NL + vidx) << 10);
  const float* W0 = (cls == 0) ? Wh : Wsh;
  const float* W1 = (cls == 0) ? Wv : Wsv;
  const float* brow0 = W0 + ((size_t)(col0 + lm) << 10);
  const float* brow1 = W1 + ((size_t)(col0 + lm) << 10);

  for (int half = 0; half < 2; ++half) {
    const float* ar = half ? arow1 : arow0;
    const float* br = half ? brow1 : brow0;
    for (int k0 = 0; k0 < ND; k0 += 16) {
      float4 av = *(const float4*)(ar + k0 + lk4);
      STORE_AS(av)
      float4 bv = *(const float4*)(br + k0 + lk4);
      STORE_BS(bv)
      __syncthreads();
      tile_compute(As, Bs, acc, tx, ty);
      __syncthreads();
    }
  }
#pragma unroll
  for (int i = 0; i < 4; ++i) {
    const int li2 = mtile * 64 + ty * 4 + i;
    if (li2 < nc) {
      const int e2 = fl[li2];
      const int it2 = e2 >> 3, t2 = e2 & 7;
      *(float4*)(edgeF + (((size_t)(it2 * 5 + t2)) << 10) + col0 + tx * 4) =
          make_float4(acc[i][0], acc[i][1], acc[i][2], acc[i][3]);
    }
  }
}

// ---------------- fp32 fixup: stF = max(0, max_t edgeF@We^T) --------------
__global__ __launch_bounds__(256) void k_fix_st(
    const int* __restrict__ cnt, const float* __restrict__ edgeF,
    const float* __restrict__ We, unsigned* __restrict__ stF) {
  const int n = (cnt[0] < MAXF) ? cnt[0] : MAXF;
  const int M = n * 5;
  const int tiles = (M + 63) >> 6;
  if ((int)blockIdx.x >= tiles) return;
  __shared__ float As[16][68];
  __shared__ float Bs[16][68];
  float acc[4][4] = {};
  const int tid = threadIdx.x;
  const int tx = tid & 15, ty = tid >> 4;
  const int row0 = blockIdx.x * 64, col0 = blockIdx.y * 64;
  const int lm = tid >> 2;
  const int lk4 = (tid & 3) * 4;
  const int r = row0 + lm;
  const int rc = (r < M) ? r : (M - 1);
  const float* arow = edgeF + ((size_t)rc << 10);
  const float* brow = We + ((size_t)(col0 + lm) << 10);
  for (int k0 = 0; k0 < NH; k0 += 16) {
    float4 av = *(const float4*)(arow + k0 + lk4);
    STORE_AS(av)
    float4 bv = *(const float4*)(brow + k0 + lk4);
    STORE_BS(bv)
    __syncthreads();
    tile_compute(As, Bs, acc, tx, ty);
    __syncthreads();
  }
#pragma unroll
  for (int i = 0; i < 4; ++i) {
    const int rr = row0 + ty * 4 + i;
    if (rr < M) {
      const int it = rr / 5;
#pragma unroll
      for (int j = 0; j < 4; ++j) {
        unsigned val = __float_as_uint(fmaxf(acc[i][j], 0.f));
        atomicMax(&stF[(size_t)it * NH + col0 + tx * 4 + j], val);
      }
    }
  }
}

// ---------------- fp32 fixup: query chain ----------------
__global__ __launch_bounds__(256) void k_fix_query(
    const int* __restrict__ cnt, const int* __restrict__ list,
    const float* __restrict__ edgeF, const float* __restrict__ stF,
    const float* __restrict__ lin, float* __restrict__ qF) {
  const int i = blockIdx.x * 256 + threadIdx.x;
  const int it = i >> 10;
  const int n = (cnt[0] < MAXF) ? cnt[0] : MAXF;
  if (it >= n) return;
  const int nn = i & (NH - 1);
  const int b = list[it];
  float e4 = edgeF[(((size_t)(it * 5 + 4)) << 10) + nn];
  float stv = stF[(size_t)it * NH + nn];
  float qt = fmaxf(e4 + stv, 0.f);
  float lb = lin[(size_t)b * NH + nn];
  float qv = fmaxf(fmaxf(qt + lb, 0.f) + lb, 0.f);
  qF[(size_t)it * NH + nn] = qv;
}

// ---------------- fp32 fixup: inp rows = qF @ Wq^T + bq -------------------
__global__ __launch_bounds__(256) void k_fix_inp(
    const int* __restrict__ cnt, const int* __restrict__ list,
    const float* __restrict__ qF, const float* __restrict__ Wq,
    const float* __restrict__ bq, float* __restrict__ inp) {
  const int n = (cnt[0] < MAXF) ? cnt[0] : MAXF;
  const int tiles = (n + 63) >> 6;
  if ((int)blockIdx.x >= tiles) return;
  __shared__ float As[16][68];
  __shared__ float Bs[16][68];
  float acc[4][4] = {};
  const int tid = threadIdx.x;
  const int tx = tid & 15, ty = tid >> 4;
  const int row0 = blockIdx.x * 64, col0 = blockIdx.y * 64;
  const int lm = tid >> 2;
  const int lk4 = (tid & 3) * 4;
  const int r = row0 + lm;
  const int rc = (r < n) ? r : (n - 1);
  const float* arow = qF + ((size_t)rc << 10);
  const float* brow = Wq + ((size_t)(col0 + lm) << 10);
  for (int k0 = 0; k0 < NH; k0 += 16) {
    float4 av = *(const float4*)(arow + k0 + lk4);
    STORE_AS(av)
    float4 bv = *(const float4*)(brow + k0 + lk4);
    STORE_BS(bv)
    __syncthreads();
    tile_compute(As, Bs, acc, tx, ty);
    __syncthreads();
  }
#pragma unroll
  for (int i = 0; i < 4; ++i) {
    const int rr = row0 + ty * 4 + i;
    if (rr < n) {
      const int b = list[rr];
      const int n0 = col0 + tx * 4;
      float4 v = make_float4(acc[i][0] + bq[n0 + 0], acc[i][1] + bq[n0 + 1],
                             acc[i][2] + bq[n0 + 2], acc[i][3] + bq[n0 + 3]);
      *(float4*)(inp + ((size_t)b << 10) + n0) = v;
    }
  }
}

// ---------------- fp32 att recompute for flagged rows ----------------
__global__ __launch_bounds__(256) void k_fixup_att(
    const int* __restrict__ cnt, const int* __restrict__ list,
    const float* __restrict__ enc, const float* __restrict__ Wc,
    const float* __restrict__ bc, const float* __restrict__ V4,
    const float* __restrict__ inp, const int* __restrict__ mask,
    float* __restrict__ att) {
  const int kq = blockIdx.x;
  const int tid = threadIdx.x;
  __shared__ float sEnc[NL][ND];
  __shared__ float sm[256];
  const int n = (cnt[0] < MAXF) ? cnt[0] : MAXF;
  for (int it = blockIdx.y; it < n; it += gridDim.y) {
    const int b = list[it];
    for (int i = tid; i < NL * 256; i += 256) {
      const int l = i >> 8, c = (i & 255) * 4;
      *(float4*)&sEnc[l][c] = *(const float4*)(enc + (((size_t)b * NL + l) << 10) + c);
    }
    __syncthreads();
    float accl[NL];
#pragma unroll
    for (int l = 0; l < NL; ++l) accl[l] = 0.f;
    for (int hp = 0; hp < 2; ++hp) {
      const int h0 = tid + hp * 512;
      const int h1 = h0 + 256;
      const float* w0 = Wc + (((size_t)kq * NH + h0) << 10);
      const float* w1 = Wc + (((size_t)kq * NH + h1) << 10);
      float d0[NL], d1[NL];
#pragma unroll
      for (int l = 0; l < NL; ++l) { d0[l] = 0.f; d1[l] = 0.f; }
      for (int k = 0; k < ND; k += 4) {
        float4 a = *(const float4*)(w0 + k);
        float4 c = *(const float4*)(w1 + k);
#pragma unroll
        for (int l = 0; l < NL; ++l) {
          float4 e = *(const float4*)&sEnc[l][k];
          d0[l] += a.x * e.x + a.y * e.y + a.z * e.z + a.w * e.w;
          d1[l] += c.x * e.x + c.y * e.y + c.z * e.z + c.w * e.w;
        }
      }
      const float i0 = inp[(size_t)b * NH + h0], i1 = inp[(size_t)b * NH + h1];
      const float b0 = bc[kq * NH + h0], b1 = bc[kq * NH + h1];
      const float v0 = V4[kq * NH + h0], v1 = V4[kq * NH + h1];
#pragma unroll
      for (int l = 0; l < NL; ++l)
        accl[l] += v0 * tanhf(d0[l] + i0 + b0) + v1 * tanhf(d1[l] + i1 + b1);
    }
    for (int l = 0; l < NL; ++l) {
      sm[tid] = accl[l];
      __syncthreads();
      for (int s = 128; s > 0; s >>= 1) {
        if (tid < s) sm[tid] += sm[tid + s];
        __syncthreads();
      }
      if (tid == 0) {
        float a = (mask[b * NL + l] != 0) ? (10.f * tanhf(sm[0])) : -10.f;
        att[b * 28 + kq * NL + l] = a;
      }
      __syncthreads();
    }
    __syncthreads();
  }
}

// ---------------- re-sample flagged rows with fixed att ----------------
__global__ __launch_bounds__(256) void k_resample(
    const int* __restrict__ flag, const float* __restrict__ att,
    const float* __restrict__ Mv, const float* __restrict__ Sv,
    const int* __restrict__ mask, float* __restrict__ out) {
  const int b = blockIdx.x * 256 + threadIdx.x;
  if (b >= NB) return;
  if (!flag[b]) return;
  float best = -INFINITY;
  int bj = 0;
  for (int j = 0; j < 28; ++j) {
    float y = (att[b * 28 + j] - Mv[j]) - logf(Sv[j]) + gumbel_for(b, j);
    if (y > best) { best = y; bj = j; }
  }
  out[b] = (float)bj;
  out[NB + b] = expf(att[b * 28 + bj] - Mv[bj]) / Sv[bj];
  const int* mrow = mask + b * NL;
#pragma unroll
  for (int l = 0; l < NL; ++l)
    out[2 * NB + (size_t)b * NL + l] = (float)(mrow[l] - ((l == bj) ? 1 : 0));
}

extern "C" void kernel_launch(void* const* d_in, const int* in_sizes, int n_in,
                              void* d_out, int out_size, void* d_ws, size_t ws_size,
                              hipStream_t stream) {
  const float* enc  = (const float*)d_in[0];
  const int*   xes  = (const int*)d_in[1];
  const int*   idx  = (const int*)d_in[2];
  const int*   mask = (const int*)d_in[3];
  const float* Wq   = (const float*)d_in[4];
  const float* bq   = (const float*)d_in[5];
  const float* Wc   = (const float*)d_in[6];
  const float* bc   = (const float*)d_in[7];
  const float* V4   = (const float*)d_in[8];
  const float* Wi   = (const float*)d_in[9];
  const float* bi   = (const float*)d_in[10];
  const float* Wh   = (const float*)d_in[11];
  const float* Wv   = (const float*)d_in[12];
  const float* Wsh  = (const float*)d_in[13];
  const float* Wsv  = (const float*)d_in[14];
  const float* We   = (const float*)d_in[15];
  (void)in_sizes; (void)n_in; (void)out_size; (void)ws_size;

  // ---- workspace layout (~340 MB) ----
  char* p = (char*)d_ws;
  float* edge4 = (float*)p;                 p += (size_t)NB * NH * 4;
  unsigned* ehilo = (unsigned*)p;           p += (size_t)NSTEP * NB * NH * 4;
  float* st = (float*)p;                    p += (size_t)NB * NH * 4;
  float* lin = (float*)p;                   p += (size_t)NB * NH * 4;
  float* query = (float*)p;                 p += (size_t)NB * NH * 4;
  float* inp = (float*)p;                   p += (size_t)NB * NH * 4;
  float* att = (float*)p;                   p += (size_t)NB * 28 * 4;
  float* Mv = (float*)p;                    p += 28 * 4;
  float* Sv = (float*)p;                    p += 28 * 4;
  int* flag = (int*)p;                      p += NB * 4;
  int* cnt = (int*)p;                       p += 4 * 4;
  int* list = (int*)p;                      p += NB * 4;
  int* cls_cnt = (int*)p;                   p += 2 * 4;
  int* l0 = (int*)p;                        p += NSTEP * NB * 4;
  int* l1 = (int*)p;                        p += NSTEP * NB * 4;
  int* fl_cnt = (int*)p;                    p += 2 * 4;
  int* fl0 = (int*)p;                       p += NSTEP * MAXF * 4;
  int* fl1 = (int*)p;                       p += NSTEP * MAXF * 4;
  float* edgeF = (float*)p;                 p += (size_t)NSTEP * MAXF * NH * 4; // 21 MB
  float* stF = (float*)p;                   p += (size_t)MAXF * NH * 4;         // 4.2 MB
  float* qF = (float*)p;                    p += (size_t)MAXF * NH * 4;         // 4.2 MB
  unsigned short* enc_hi = (unsigned short*)p; p += (size_t)NB * NL * ND * 2;
  unsigned short* enc_lo = (unsigned short*)p; p += (size_t)NB * NL * ND * 2;
  unsigned short* w4hi = (unsigned short*)p;   p += (size_t)4 * NH * ND * 2;
  unsigned short* w4lo = (unsigned short*)p;   p += (size_t)4 * NH * ND * 2;
  unsigned short* wehi = (unsigned short*)p;   p += (size_t)NH * ND * 2;
  unsigned short* welo = (unsigned short*)p;   p += (size_t)NH * ND * 2;
  unsigned short* wc_hi = (unsigned short*)p;  p += (size_t)4 * NH * ND * 2;
  unsigned short* wc_lo = (unsigned short*)p;  p += (size_t)4 * NH * ND * 2;
  float* out = (float*)d_out;

  hipMemsetAsync(st, 0, (size_t)NB * NH * sizeof(float), stream);
  hipMemsetAsync(att, 0, (size_t)NB * 28 * sizeof(float), stream);
  hipMemsetAsync(cnt, 0, sizeof(int), stream);
  hipMemsetAsync(cls_cnt, 0, 2 * sizeof(int), stream);
  hipMemsetAsync(fl_cnt, 0, 2 * sizeof(int), stream);
  hipMemsetAsync(stF, 0, (size_t)MAXF * NH * sizeof(float), stream);

  dim3 blk(256);
  // bf16 hi/lo planes
  k_split<<<dim3((NB * NL * ND) / 1024), blk, 0, stream>>>(enc, enc_hi, enc_lo);
  k_split<<<dim3((4 * NH * ND) / 1024), blk, 0, stream>>>(Wc, wc_hi, wc_lo);
  k_split<<<dim3((NH * ND) / 1024), blk, 0, stream>>>(Wh, w4hi, w4lo);
  k_split<<<dim3((NH * ND) / 1024), blk, 0, stream>>>(Wv, w4hi + (size_t)NH * ND, w4lo + (size_t)NH * ND);
  k_split<<<dim3((NH * ND) / 1024), blk, 0, stream>>>(Wsh, w4hi + (size_t)2 * NH * ND, w4lo + (size_t)2 * NH * ND);
  k_split<<<dim3((NH * ND) / 1024), blk, 0, stream>>>(Wsv, w4hi + (size_t)3 * NH * ND, w4lo + (size_t)3 * NH * ND);
  k_split<<<dim3((NH * ND) / 1024), blk, 0, stream>>>(We, wehi, welo);
  // classify rows by tt
  k_classify<<<dim3((NSTEP * NB) / 256), blk, 0, stream>>>(xes, cls_cnt, l0, l1);
  // edges via MFMA (K=2048, two classes, compacted)
  g1_mfma<<<dim3(162, 8), blk, 0, stream>>>(cls_cnt, l0, l1, xes, enc_hi, enc_lo,
                                            w4hi, w4lo, ehilo, edge4);
  // lin = gather(enc, idx) @ Wi^T + bi  (fp32)
  gemm_bias<<<dim3(16, 64), blk, 0, stream>>>(nullptr, idx, enc, Wi, bi, lin);
  // st = max(0, max_t edge@We^T) via MFMA
  g2_mfma<<<dim3(160, 8), blk, 0, stream>>>(ehilo, wehi, welo, (unsigned*)st);
  // query
  k_query<<<dim3((NB * NH) / 256), blk, 0, stream>>>(edge4, st, lin, query);
  // inp = query @ Wq^T + bq (fp32)
  gemm_bias<<<dim3(16, 64), blk, 0, stream>>>(query, nullptr, enc, Wq, bq, inp);
  // att partial sums via bf16 MFMA (3-term hi/lo)
  g5_mfma<<<dim3(224, 32), blk, 0, stream>>>(enc_hi, enc_lo, wc_hi, wc_lo,
                                             inp, bc, V4, att);
  k_finish<<<dim3((NB * 28) / 256), blk, 0, stream>>>(att, mask);
  k_colstats<<<dim3(28), blk, 0, stream>>>(att, Mv, Sv);
  k_sample<<<dim3(NB / 256), blk, 0, stream>>>(att, Mv, Sv, mask, out, flag, cnt, list);
  // fp32 fixup chain for flagged rows (GEMM-shaped, worst-case grids w/ early exit)
  k_build_fl<<<dim3(MAXF / 256), blk, 0, stream>>>(cnt, list, xes, fl_cnt, fl0, fl1);
  k_fix_edge<<<dim3(81, 16), blk, 0, stream>>>(fl_cnt, fl0, fl1, list, xes, enc,
                                               Wh, Wv, Wsh, Wsv, edgeF);
  k_fix_st<<<dim3(80, 16), blk, 0, stream>>>(cnt, edgeF, We, (unsigned*)stF);
  k_fix_query<<<dim3((MAXF * NH) / 256), blk, 0, stream>>>(cnt, list, edgeF, stF, lin, qF);
  k_fix_inp<<<dim3(16, 16), blk, 0, stream>>>(cnt, list, qF, Wq, bq, inp);
  k_fixup_att<<<dim3(4, 64), blk, 0, stream>>>(cnt, list, enc, Wc, bc, V4, inp, mask, att);
  k_resample<<<dim3(NB / 256), blk, 0, stream>>>(flag, att, Mv, Sv, mask, out);
}

// Round 6
// 3236.057 us; speedup vs baseline: 2.3364x; 1.0637x over previous
//
#include <hip/hip_runtime.h>

// Problem dims (fixed)
#define NB 4096   // B
#define NL 7      // L
#define ND 1024   // D
#define NH 1024   // H
#define NT 6      // T
#define NSTEP 5   // effective scan steps (t = 0..4)
#define GAP 0.02f // gumbel top-2 gap below which we recompute the row in fp32
#define MAXF 1024 // max flagged rows handled by the fp32 fixup chain (~10x margin)

typedef __attribute__((ext_vector_type(8))) short bf16x8;
typedef __attribute__((ext_vector_type(4))) float f32x4;

// ---------------- threefry2x32 (JAX-compatible, 20 rounds) ----------------
__device__ __forceinline__ unsigned rotl32(unsigned x, int r) {
  return (x << r) | (x >> (32 - r));
}

__device__ __forceinline__ void threefry2x32(unsigned k0, unsigned k1,
                                             unsigned x0, unsigned x1,
                                             unsigned& o0, unsigned& o1) {
  unsigned ks2 = k0 ^ k1 ^ 0x1BD11BDAu;
#define TFR(R) { x0 += x1; x1 = rotl32(x1, (R)); x1 ^= x0; }
  x0 += k0; x1 += k1;
  TFR(13) TFR(15) TFR(26) TFR(6)
  x0 += k1; x1 += ks2 + 1u;
  TFR(17) TFR(29) TFR(16) TFR(24)
  x0 += ks2; x1 += k0 + 2u;
  TFR(13) TFR(15) TFR(26) TFR(6)
  x0 += k0; x1 += k1 + 3u;
  TFR(17) TFR(29) TFR(16) TFR(24)
  x0 += k1; x1 += ks2 + 4u;
  TFR(13) TFR(15) TFR(26) TFR(6)
  x0 += ks2; x1 += k0 + 5u;
#undef TFR
  o0 = x0; o1 = x1;
}

__device__ __forceinline__ float gumbel_for(int b, int j) {
  unsigned o0, o1;
  threefry2x32(0u, 42u, 0u, (unsigned)(b * 28 + j), o0, o1);
  unsigned bits = o0 ^ o1;
  const float TINY = 1.17549435e-38f;
  float u = __uint_as_float((bits >> 9) | 0x3f800000u) - 1.0f;
  u = fmaxf(TINY, u + TINY);
  return -logf(-logf(u));
}

// ---------------- bf16 hi/lo split ----------------
__device__ __forceinline__ unsigned short f2bf(float f) {
  unsigned u = __float_as_uint(f);
  unsigned r = u + 0x7FFFu + ((u >> 16) & 1u);
  return (unsigned short)(r >> 16);
}
__device__ __forceinline__ float bf2f(unsigned short h) {
  return __uint_as_float(((unsigned)h) << 16);
}

__global__ __launch_bounds__(256) void k_split(
    const float* __restrict__ x, unsigned short* __restrict__ hi,
    unsigned short* __restrict__ lo) {
  const size_t i = ((size_t)blockIdx.x * 256 + threadIdx.x) * 4;
  float4 v = *(const float4*)(x + i);
  ushort4 h, l;
  h.x = f2bf(v.x); l.x = f2bf(v.x - bf2f(h.x));
  h.y = f2bf(v.y); l.y = f2bf(v.y - bf2f(h.y));
  h.z = f2bf(v.z); l.z = f2bf(v.z - bf2f(h.z));
  h.w = f2bf(v.w); l.w = f2bf(v.w - bf2f(h.w));
  *(ushort4*)(hi + i) = h;
  *(ushort4*)(lo + i) = l;
}

// ---------------- shared 64x64 fp32 tile core (fixup GEMMs) ------
__device__ __forceinline__ void tile_compute(const float (*As)[68],
                                             const float (*Bs)[68],
                                             float acc[4][4], int tx, int ty) {
#pragma unroll
  for (int kk = 0; kk < 16; ++kk) {
    float4 a  = *(const float4*)&As[kk][ty * 4];
    float4 bb = *(const float4*)&Bs[kk][tx * 4];
    acc[0][0] += a.x * bb.x; acc[0][1] += a.x * bb.y; acc[0][2] += a.x * bb.z; acc[0][3] += a.x * bb.w;
    acc[1][0] += a.y * bb.x; acc[1][1] += a.y * bb.y; acc[1][2] += a.y * bb.z; acc[1][3] += a.y * bb.w;
    acc[2][0] += a.z * bb.x; acc[2][1] += a.z * bb.y; acc[2][2] += a.z * bb.z; acc[2][3] += a.z * bb.w;
    acc[3][0] += a.w * bb.x; acc[3][1] += a.w * bb.y; acc[3][2] += a.w * bb.z; acc[3][3] += a.w * bb.w;
  }
}

#define STORE_AS(av) { As[lk4+0][lm]=(av).x; As[lk4+1][lm]=(av).y; As[lk4+2][lm]=(av).z; As[lk4+3][lm]=(av).w; }
#define STORE_BS(bv) { Bs[lk4+0][lm]=(bv).x; Bs[lk4+1][lm]=(bv).y; Bs[lk4+2][lm]=(bv).z; Bs[lk4+3][lm]=(bv).w; }

// ---------------- classify rows (t,b) by tt ----------------
__global__ __launch_bounds__(256) void k_classify(
    const int* __restrict__ xes, int* __restrict__ cls_cnt,
    int* __restrict__ l0, int* __restrict__ l1) {
  const int r = blockIdx.x * 256 + threadIdx.x;
  if (r >= NSTEP * NB) return;
  const int b = r & (NB - 1), t = r >> 12;
  const int tt = xes[(b * NT + t) * 3 + 2];
  if (tt == 0) { int p = atomicAdd(&cls_cnt[0], 1); l0[p] = r; }
  else         { int p = atomicAdd(&cls_cnt[1], 1); l1[p] = r; }
}

// ---------------- G1 (bf16 MFMA): edges, K=2048 per class ----------------
// grid (8, 162): x = N-tile (fast, for A-stripe L2 locality), y = class tile.
__global__ __launch_bounds__(256) void g1_mfma(
    const int* __restrict__ cls_cnt, const int* __restrict__ l0,
    const int* __restrict__ l1, const int* __restrict__ xes,
    const unsigned short* __restrict__ enc_hi, const unsigned short* __restrict__ enc_lo,
    const unsigned short* __restrict__ w4hi, const unsigned short* __restrict__ w4lo,
    unsigned* __restrict__ ehilo, float* __restrict__ edge4) {
  const int n0c = cls_cnt[0], n1c = cls_cnt[1];
  const int tiles0 = (n0c + 127) >> 7, tiles1 = (n1c + 127) >> 7;
  const int bx = blockIdx.y;
  if (bx >= tiles0 + tiles1) return;
  int cls, mtile, nc;
  const int* list;
  if (bx < tiles0) { cls = 0; mtile = bx; nc = n0c; list = l0; }
  else { cls = 1; mtile = bx - tiles0; nc = n1c; list = l1; }

  __shared__ unsigned short sAhi[4096], sAlo[4096], sBhi[4096], sBlo[4096];
  const int tid = threadIdx.x;
  const int ncol0 = blockIdx.x * 128;

  const int ri = tid & 127;
  const int c0 = tid >> 7;
  const int c1 = c0 + 2;
  const int li = mtile * 128 + ri;
  const int rsrc = list[(li < nc) ? li : (nc - 1)];
  const int b = rsrc & (NB - 1), t = rsrc >> 12;
  const int hidx = xes[(b * NT + t) * 3 + 0];
  const int vidx = xes[(b * NT + t) * 3 + 1];
  const unsigned short* ha = enc_hi + (((size_t)b * NL + hidx) << 10);
  const unsigned short* la = enc_lo + (((size_t)b * NL + hidx) << 10);
  const unsigned short* hb = enc_hi + (((size_t)b * NL + vidx) << 10);
  const unsigned short* lb = enc_lo + (((size_t)b * NL + vidx) << 10);
  const size_t wrow = ((size_t)(ncol0 + ri)) << 10;

  const int wave = tid >> 6, lane = tid & 63;
  const int wm = wave >> 1, wn = wave & 1;
  const int q = lane >> 4, m16 = lane & 15;

  f32x4 acc[4][4] = {};

  for (int kt = 0; kt < 64; ++kt) {
    const int seg = (kt < 32) ? (cls * 2) : (cls * 2 + 1);
    const int kl = (kt & 31) * 32;
    const unsigned short* ah = (kt < 32) ? ha : hb;
    const unsigned short* al = (kt < 32) ? la : lb;
    bf16x8 vah0 = *(const bf16x8*)(ah + kl + c0 * 8);
    bf16x8 vah1 = *(const bf16x8*)(ah + kl + c1 * 8);
    bf16x8 val0 = *(const bf16x8*)(al + kl + c0 * 8);
    bf16x8 val1 = *(const bf16x8*)(al + kl + c1 * 8);
    const unsigned short* wh = w4hi + (((size_t)seg) << 20) + wrow + kl;
    const unsigned short* wl = w4lo + (((size_t)seg) << 20) + wrow + kl;
    bf16x8 vbh0 = *(const bf16x8*)(wh + c0 * 8);
    bf16x8 vbh1 = *(const bf16x8*)(wh + c1 * 8);
    bf16x8 vbl0 = *(const bf16x8*)(wl + c0 * 8);
    bf16x8 vbl1 = *(const bf16x8*)(wl + c1 * 8);
    *(bf16x8*)&sAhi[(c0 * 128 + ri) * 8] = vah0;
    *(bf16x8*)&sAhi[(c1 * 128 + ri) * 8] = vah1;
    *(bf16x8*)&sAlo[(c0 * 128 + ri) * 8] = val0;
    *(bf16x8*)&sAlo[(c1 * 128 + ri) * 8] = val1;
    *(bf16x8*)&sBhi[(c0 * 128 + ri) * 8] = vbh0;
    *(bf16x8*)&sBhi[(c1 * 128 + ri) * 8] = vbh1;
    *(bf16x8*)&sBlo[(c0 * 128 + ri) * 8] = vbl0;
    *(bf16x8*)&sBlo[(c1 * 128 + ri) * 8] = vbl1;
    __syncthreads();

    bf16x8 bh[4], bl[4];
#pragma unroll
    for (int tn = 0; tn < 4; ++tn) {
      const int nl = wn * 64 + tn * 16 + m16;
      bh[tn] = *(const bf16x8*)&sBhi[(q * 128 + nl) * 8];
      bl[tn] = *(const bf16x8*)&sBlo[(q * 128 + nl) * 8];
    }
#pragma unroll
    for (int tm = 0; tm < 4; ++tm) {
      const int ml = wm * 64 + tm * 16 + m16;
      bf16x8 ah8 = *(const bf16x8*)&sAhi[(q * 128 + ml) * 8];
      bf16x8 al8 = *(const bf16x8*)&sAlo[(q * 128 + ml) * 8];
#pragma unroll
      for (int tn = 0; tn < 4; ++tn) {
        acc[tm][tn] = __builtin_amdgcn_mfma_f32_16x16x32_bf16(ah8, bh[tn], acc[tm][tn], 0, 0, 0);
        acc[tm][tn] = __builtin_amdgcn_mfma_f32_16x16x32_bf16(al8, bh[tn], acc[tm][tn], 0, 0, 0);
        acc[tm][tn] = __builtin_amdgcn_mfma_f32_16x16x32_bf16(ah8, bl[tn], acc[tm][tn], 0, 0, 0);
      }
    }
    __syncthreads();
  }

#pragma unroll
  for (int tm = 0; tm < 4; ++tm) {
#pragma unroll
    for (int j = 0; j < 4; ++j) {
      const int rl = wm * 64 + tm * 16 + q * 4 + j;
      const int li2 = mtile * 128 + rl;
      if (li2 < nc) {
        const int rr = list[li2];
#pragma unroll
        for (int tn = 0; tn < 4; ++tn) {
          const int n = ncol0 + wn * 64 + tn * 16 + m16;
          const float val = acc[tm][tn][j];
          unsigned short h = f2bf(val);
          unsigned short l = f2bf(val - bf2f(h));
          ehilo[(size_t)rr * NH + n] = (unsigned)h | ((unsigned)l << 16);
          if (rr >= 4 * NB) edge4[(size_t)(rr - 4 * NB) * NH + n] = val;
        }
      }
    }
  }
}

// ---------------- G2 (bf16 MFMA): st = max(0, max_t edge@We^T) ------------
// grid (8, 160): x = N-tile (fast), y = M-tile.
__global__ __launch_bounds__(256) void g2_mfma(
    const unsigned* __restrict__ ehilo,
    const unsigned short* __restrict__ wehi, const unsigned short* __restrict__ welo,
    unsigned* __restrict__ st) {
  __shared__ unsigned short sAhi[4096], sAlo[4096], sBhi[4096], sBlo[4096];
  const int tid = threadIdx.x;
  const int row0 = blockIdx.y * 128;
  const int ncol0 = blockIdx.x * 128;

  const int ri = tid & 127;
  const int c0 = tid >> 7;
  const int c1 = c0 + 2;
  const size_t arow = (size_t)(row0 + ri) * NH;
  const size_t wrow = ((size_t)(ncol0 + ri)) << 10;

  const int wave = tid >> 6, lane = tid & 63;
  const int wm = wave >> 1, wn = wave & 1;
  const int q = lane >> 4, m16 = lane & 15;

  f32x4 acc[4][4] = {};

  for (int kt = 0; kt < 32; ++kt) {
    const int kl = kt * 32;
    uint4 p00 = *(const uint4*)(ehilo + arow + kl + c0 * 8);
    uint4 p01 = *(const uint4*)(ehilo + arow + kl + c0 * 8 + 4);
    uint4 p10 = *(const uint4*)(ehilo + arow + kl + c1 * 8);
    uint4 p11 = *(const uint4*)(ehilo + arow + kl + c1 * 8 + 4);
    bf16x8 ah0, al0, ah1, al1;
    {
      unsigned u[8] = {p00.x, p00.y, p00.z, p00.w, p01.x, p01.y, p01.z, p01.w};
#pragma unroll
      for (int i = 0; i < 8; ++i) { ah0[i] = (short)(u[i] & 0xffff); al0[i] = (short)(u[i] >> 16); }
      unsigned v[8] = {p10.x, p10.y, p10.z, p10.w, p11.x, p11.y, p11.z, p11.w};
#pragma unroll
      for (int i = 0; i < 8; ++i) { ah1[i] = (short)(v[i] & 0xffff); al1[i] = (short)(v[i] >> 16); }
    }
    bf16x8 vbh0 = *(const bf16x8*)(wehi + wrow + kl + c0 * 8);
    bf16x8 vbh1 = *(const bf16x8*)(wehi + wrow + kl + c1 * 8);
    bf16x8 vbl0 = *(const bf16x8*)(welo + wrow + kl + c0 * 8);
    bf16x8 vbl1 = *(const bf16x8*)(welo + wrow + kl + c1 * 8);
    *(bf16x8*)&sAhi[(c0 * 128 + ri) * 8] = ah0;
    *(bf16x8*)&sAhi[(c1 * 128 + ri) * 8] = ah1;
    *(bf16x8*)&sAlo[(c0 * 128 + ri) * 8] = al0;
    *(bf16x8*)&sAlo[(c1 * 128 + ri) * 8] = al1;
    *(bf16x8*)&sBhi[(c0 * 128 + ri) * 8] = vbh0;
    *(bf16x8*)&sBhi[(c1 * 128 + ri) * 8] = vbh1;
    *(bf16x8*)&sBlo[(c0 * 128 + ri) * 8] = vbl0;
    *(bf16x8*)&sBlo[(c1 * 128 + ri) * 8] = vbl1;
    __syncthreads();

    bf16x8 bh[4], bl[4];
#pragma unroll
    for (int tn = 0; tn < 4; ++tn) {
      const int nl = wn * 64 + tn * 16 + m16;
      bh[tn] = *(const bf16x8*)&sBhi[(q * 128 + nl) * 8];
      bl[tn] = *(const bf16x8*)&sBlo[(q * 128 + nl) * 8];
    }
#pragma unroll
    for (int tm = 0; tm < 4; ++tm) {
      const int ml = wm * 64 + tm * 16 + m16;
      bf16x8 ah8 = *(const bf16x8*)&sAhi[(q * 128 + ml) * 8];
      bf16x8 al8 = *(const bf16x8*)&sAlo[(q * 128 + ml) * 8];
#pragma unroll
      for (int tn = 0; tn < 4; ++tn) {
        acc[tm][tn] = __builtin_amdgcn_mfma_f32_16x16x32_bf16(ah8, bh[tn], acc[tm][tn], 0, 0, 0);
        acc[tm][tn] = __builtin_amdgcn_mfma_f32_16x16x32_bf16(al8, bh[tn], acc[tm][tn], 0, 0, 0);
        acc[tm][tn] = __builtin_amdgcn_mfma_f32_16x16x32_bf16(ah8, bl[tn], acc[tm][tn], 0, 0, 0);
      }
    }
    __syncthreads();
  }

#pragma unroll
  for (int tm = 0; tm < 4; ++tm) {
#pragma unroll
    for (int j = 0; j < 4; ++j) {
      const int rr = row0 + wm * 64 + tm * 16 + q * 4 + j;
      const int b = rr & (NB - 1);
#pragma unroll
      for (int tn = 0; tn < 4; ++tn) {
        const int n = ncol0 + wn * 64 + tn * 16 + m16;
        unsigned val = __float_as_uint(fmaxf(acc[tm][tn][j], 0.f));
        atomicMax(&st[(size_t)b * NH + n], val);
      }
    }
  }
}

// ------- g_lin (bf16 MFMA): C = A@B^T + bias, M=4096, N=1024, K=1024 ------
// grid (8, 32): x = N-tile (fast), y = M-tile. Optional A gather via gidx.
__global__ __launch_bounds__(256) void g_lin_mfma(
    const unsigned short* __restrict__ Ahi, const unsigned short* __restrict__ Alo,
    const int* __restrict__ gidx,
    const unsigned short* __restrict__ Bhi, const unsigned short* __restrict__ Blo,
    const float* __restrict__ bias, float* __restrict__ C) {
  __shared__ __align__(16) char smem[32768];
  unsigned short* sAhi = (unsigned short*)smem;
  unsigned short* sAlo = (unsigned short*)(smem + 8192);
  unsigned short* sBhi = (unsigned short*)(smem + 16384);
  unsigned short* sBlo = (unsigned short*)(smem + 24576);
  const int tid = threadIdx.x;
  const int row0 = blockIdx.y * 128;
  const int ncol0 = blockIdx.x * 128;
  const int s0 = tid, s1 = tid + 256;
  const int c0 = s0 >> 7, r0 = s0 & 127;
  const int c1 = s1 >> 7, r1 = s1 & 127;
  const int ar0 = row0 + r0, ar1 = row0 + r1;
  size_t abase0 = gidx ? (((size_t)(ar0 * NL + gidx[ar0])) << 10) : ((size_t)ar0 << 10);
  size_t abase1 = gidx ? (((size_t)(ar1 * NL + gidx[ar1])) << 10) : ((size_t)ar1 << 10);
  size_t aoff0 = abase0 + c0 * 8;
  size_t aoff1 = abase1 + c1 * 8;
  size_t boff0 = (size_t)(ncol0 + r0) * ND + c0 * 8;
  size_t boff1 = (size_t)(ncol0 + r1) * ND + c1 * 8;

  const int wave = tid >> 6, lane = tid & 63;
  const int wm = wave >> 1, wn = wave & 1;
  const int q = lane >> 4, m16 = lane & 15;

  f32x4 acc[4][4] = {};

  for (int kt = 0; kt < 32; ++kt) {
    bf16x8 vah0 = *(const bf16x8*)(Ahi + aoff0);
    bf16x8 vah1 = *(const bf16x8*)(Ahi + aoff1);
    bf16x8 val0 = *(const bf16x8*)(Alo + aoff0);
    bf16x8 val1 = *(const bf16x8*)(Alo + aoff1);
    bf16x8 vbh0 = *(const bf16x8*)(Bhi + boff0);
    bf16x8 vbh1 = *(const bf16x8*)(Bhi + boff1);
    bf16x8 vbl0 = *(const bf16x8*)(Blo + boff0);
    bf16x8 vbl1 = *(const bf16x8*)(Blo + boff1);
    *(bf16x8*)&sAhi[s0 * 8] = vah0;
    *(bf16x8*)&sAhi[s1 * 8] = vah1;
    *(bf16x8*)&sAlo[s0 * 8] = val0;
    *(bf16x8*)&sAlo[s1 * 8] = val1;
    *(bf16x8*)&sBhi[s0 * 8] = vbh0;
    *(bf16x8*)&sBhi[s1 * 8] = vbh1;
    *(bf16x8*)&sBlo[s0 * 8] = vbl0;
    *(bf16x8*)&sBlo[s1 * 8] = vbl1;
    __syncthreads();

    bf16x8 bh[4], bl[4];
#pragma unroll
    for (int tn = 0; tn < 4; ++tn) {
      const int nl = wn * 64 + tn * 16 + m16;
      bh[tn] = *(const bf16x8*)&sBhi[(q * 128 + nl) * 8];
      bl[tn] = *(const bf16x8*)&sBlo[(q * 128 + nl) * 8];
    }
#pragma unroll
    for (int tm = 0; tm < 4; ++tm) {
      const int ml = wm * 64 + tm * 16 + m16;
      bf16x8 ah = *(const bf16x8*)&sAhi[(q * 128 + ml) * 8];
      bf16x8 al = *(const bf16x8*)&sAlo[(q * 128 + ml) * 8];
#pragma unroll
      for (int tn = 0; tn < 4; ++tn) {
        acc[tm][tn] = __builtin_amdgcn_mfma_f32_16x16x32_bf16(ah, bh[tn], acc[tm][tn], 0, 0, 0);
        acc[tm][tn] = __builtin_amdgcn_mfma_f32_16x16x32_bf16(al, bh[tn], acc[tm][tn], 0, 0, 0);
        acc[tm][tn] = __builtin_amdgcn_mfma_f32_16x16x32_bf16(ah, bl[tn], acc[tm][tn], 0, 0, 0);
      }
    }
    __syncthreads();
    aoff0 += 32; aoff1 += 32; boff0 += 32; boff1 += 32;
  }

#pragma unroll
  for (int tm = 0; tm < 4; ++tm) {
#pragma unroll
    for (int j = 0; j < 4; ++j) {
      const int R = row0 + wm * 64 + tm * 16 + q * 4 + j;
#pragma unroll
      for (int tn = 0; tn < 4; ++tn) {
        const int n = ncol0 + wn * 64 + tn * 16 + m16;
        C[(size_t)R * NH + n] = acc[tm][tn][j] + bias[n];
      }
    }
  }
}

// ---------------- G5 (bf16 MFMA): fused ctx GEMM + tanh + V4 reduce --------
// grid (32, 224): x = N-tile (fast), y = M-tile. 32 KB LDS (red aliased).
__global__ __launch_bounds__(256) void g5_mfma(
    const unsigned short* __restrict__ Ahi, const unsigned short* __restrict__ Alo,
    const unsigned short* __restrict__ Bhi, const unsigned short* __restrict__ Blo,
    const float* __restrict__ inp, const float* __restrict__ bc,
    const float* __restrict__ V4, float* __restrict__ att) {
  __shared__ __align__(16) char smem[32768];
  unsigned short* sAhi = (unsigned short*)smem;
  unsigned short* sAlo = (unsigned short*)(smem + 8192);
  unsigned short* sBhi = (unsigned short*)(smem + 16384);
  unsigned short* sBlo = (unsigned short*)(smem + 24576);
  float (*red)[33] = (float(*)[33])smem;  // aliased onto dead staging (16.9 KB)

  const int tid = threadIdx.x;
  const int row0 = blockIdx.y * 128;   // M-tile (224)
  const int ncol0 = blockIdx.x * 128;  // N-tile (32)

  const int s0 = tid, s1 = tid + 256;
  const int c0 = s0 >> 7, r0 = s0 & 127;
  const int c1 = s1 >> 7, r1 = s1 & 127;
  size_t aoff0 = (size_t)(row0 + r0) * ND + c0 * 8;
  size_t aoff1 = (size_t)(row0 + r1) * ND + c1 * 8;
  size_t boff0 = (size_t)(ncol0 + r0) * ND + c0 * 8;
  size_t boff1 = (size_t)(ncol0 + r1) * ND + c1 * 8;

  const int wave = tid >> 6, lane = tid & 63;
  const int wm = wave >> 1, wn = wave & 1;
  const int q = lane >> 4, m16 = lane & 15;

  f32x4 acc[4][4] = {};

  for (int kt = 0; kt < 32; ++kt) {
    bf16x8 vah0 = *(const bf16x8*)(Ahi + aoff0);
    bf16x8 vah1 = *(const bf16x8*)(Ahi + aoff1);
    bf16x8 val0 = *(const bf16x8*)(Alo + aoff0);
    bf16x8 val1 = *(const bf16x8*)(Alo + aoff1);
    bf16x8 vbh0 = *(const bf16x8*)(Bhi + boff0);
    bf16x8 vbh1 = *(const bf16x8*)(Bhi + boff1);
    bf16x8 vbl0 = *(const bf16x8*)(Blo + boff0);
    bf16x8 vbl1 = *(const bf16x8*)(Blo + boff1);
    *(bf16x8*)&sAhi[s0 * 8] = vah0;
    *(bf16x8*)&sAhi[s1 * 8] = vah1;
    *(bf16x8*)&sAlo[s0 * 8] = val0;
    *(bf16x8*)&sAlo[s1 * 8] = val1;
    *(bf16x8*)&sBhi[s0 * 8] = vbh0;
    *(bf16x8*)&sBhi[s1 * 8] = vbh1;
    *(bf16x8*)&sBlo[s0 * 8] = vbl0;
    *(bf16x8*)&sBlo[s1 * 8] = vbl1;
    __syncthreads();

    bf16x8 bh[4], bl[4];
#pragma unroll
    for (int tn = 0; tn < 4; ++tn) {
      const int nl = wn * 64 + tn * 16 + m16;
      bh[tn] = *(const bf16x8*)&sBhi[(q * 128 + nl) * 8];
      bl[tn] = *(const bf16x8*)&sBlo[(q * 128 + nl) * 8];
    }
#pragma unroll
    for (int tm = 0; tm < 4; ++tm) {
      const int ml = wm * 64 + tm * 16 + m16;
      bf16x8 ah = *(const bf16x8*)&sAhi[(q * 128 + ml) * 8];
      bf16x8 al = *(const bf16x8*)&sAlo[(q * 128 + ml) * 8];
#pragma unroll
      for (int tn = 0; tn < 4; ++tn) {
        acc[tm][tn] = __builtin_amdgcn_mfma_f32_16x16x32_bf16(ah, bh[tn], acc[tm][tn], 0, 0, 0);
        acc[tm][tn] = __builtin_amdgcn_mfma_f32_16x16x32_bf16(al, bh[tn], acc[tm][tn], 0, 0, 0);
        acc[tm][tn] = __builtin_amdgcn_mfma_f32_16x16x32_bf16(ah, bl[tn], acc[tm][tn], 0, 0, 0);
      }
    }
    __syncthreads();
    aoff0 += 32; aoff1 += 32; boff0 += 32; boff1 += 32;
  }
  // K-loop ended with a barrier: staging LDS is dead, red may alias it.

  const int kq = ncol0 >> 10;
  float rowsum[16];
#pragma unroll
  for (int i = 0; i < 16; ++i) rowsum[i] = 0.f;
#pragma unroll
  for (int tm = 0; tm < 4; ++tm) {
#pragma unroll
    for (int tn = 0; tn < 4; ++tn) {
      const int n = ncol0 + wn * 64 + tn * 16 + m16;
      const int h = n & (NH - 1);
      const float v4 = V4[kq * NH + h];
      const float bcv = bc[kq * NH + h];
#pragma unroll
      for (int j = 0; j < 4; ++j) {
        const int R = row0 + wm * 64 + tm * 16 + q * 4 + j;
        const int b = R / NL;
        float val = acc[tm][tn][j] + inp[(size_t)b * NH + h] + bcv;
        rowsum[tm * 4 + j] += v4 * tanhf(val);
      }
    }
  }
#pragma unroll
  for (int tm = 0; tm < 4; ++tm)
#pragma unroll
    for (int j = 0; j < 4; ++j)
      red[wm * 64 + tm * 16 + q * 4 + j][wn * 16 + m16] = rowsum[tm * 4 + j];
  __syncthreads();
  if (tid < 128) {
    float ssum = 0.f;
#pragma unroll
    for (int x = 0; x < 32; ++x) ssum += red[tid][x];
    const int R = row0 + tid;
    const int b = R / NL, l = R - b * NL;
    atomicAdd(&att[b * 28 + kq * NL + l], ssum);
  }
}

// ------- elementwise: query chain -> bf16 hi/lo planes ----------------
__global__ __launch_bounds__(256) void k_query(
    const float* __restrict__ edge4, const float* __restrict__ st,
    const float* __restrict__ lin, unsigned short* __restrict__ qhi,
    unsigned short* __restrict__ qlo) {
  const size_t i = ((size_t)blockIdx.x * 256 + threadIdx.x) * 4;
  float4 e4 = *(const float4*)(edge4 + i);
  float4 sv = *(const float4*)(st + i);
  float4 lv = *(const float4*)(lin + i);
  float qv[4];
  qv[0] = fmaxf(fmaxf(fmaxf(e4.x + sv.x, 0.f) + lv.x, 0.f) + lv.x, 0.f);
  qv[1] = fmaxf(fmaxf(fmaxf(e4.y + sv.y, 0.f) + lv.y, 0.f) + lv.y, 0.f);
  qv[2] = fmaxf(fmaxf(fmaxf(e4.z + sv.z, 0.f) + lv.z, 0.f) + lv.z, 0.f);
  qv[3] = fmaxf(fmaxf(fmaxf(e4.w + sv.w, 0.f) + lv.w, 0.f) + lv.w, 0.f);
  ushort4 h, l;
  h.x = f2bf(qv[0]); l.x = f2bf(qv[0] - bf2f(h.x));
  h.y = f2bf(qv[1]); l.y = f2bf(qv[1] - bf2f(h.y));
  h.z = f2bf(qv[2]); l.z = f2bf(qv[2] - bf2f(h.z));
  h.w = f2bf(qv[3]); l.w = f2bf(qv[3] - bf2f(h.w));
  *(ushort4*)(qhi + i) = h;
  *(ushort4*)(qlo + i) = l;
}

// ---------------- att finish: mask -> -inf -> 10*tanh ----------------
__global__ __launch_bounds__(256) void k_finish(
    float* __restrict__ att, const int* __restrict__ mask) {
  const int i = blockIdx.x * 256 + threadIdx.x;
  const int b = i / 28;
  const int j = i - b * 28;
  const int l = j % NL;
  float v = att[i];
  att[i] = (mask[b * NL + l] != 0) ? (10.f * tanhf(v)) : -10.f;
}

// ---------------- per-column (over B) softmax stats ----------------
__global__ __launch_bounds__(256) void k_colstats(
    const float* __restrict__ att, float* __restrict__ Mv, float* __restrict__ Sv) {
  const int j = blockIdx.x;
  const int tid = threadIdx.x;
  __shared__ float sm[256];
  float m = -INFINITY;
  for (int b = tid; b < NB; b += 256) m = fmaxf(m, att[b * 28 + j]);
  sm[tid] = m;
  __syncthreads();
  for (int s = 128; s > 0; s >>= 1) {
    if (tid < s) sm[tid] = fmaxf(sm[tid], sm[tid + s]);
    __syncthreads();
  }
  const float M = sm[0];
  __syncthreads();
  float sum = 0.f;
  for (int b = tid; b < NB; b += 256) sum += expf(att[b * 28 + j] - M);
  sm[tid] = sum;
  __syncthreads();
  for (int s = 128; s > 0; s >>= 1) {
    if (tid < s) sm[tid] += sm[tid + s];
    __syncthreads();
  }
  if (tid == 0) { Mv[j] = M; Sv[j] = sm[0]; }
}

// ---------------- sampling + close-call compaction ----------------
__global__ __launch_bounds__(256) void k_sample(
    const float* __restrict__ att, const float* __restrict__ Mv,
    const float* __restrict__ Sv, const int* __restrict__ mask,
    float* __restrict__ out, int* __restrict__ flag,
    int* __restrict__ cnt, int* __restrict__ list) {
  const int b = blockIdx.x * 256 + threadIdx.x;
  if (b >= NB) return;
  float best = -INFINITY, second = -INFINITY;
  int bj = 0;
  for (int j = 0; j < 28; ++j) {
    float y = (att[b * 28 + j] - Mv[j]) - logf(Sv[j]) + gumbel_for(b, j);
    if (y > best) { second = best; best = y; bj = j; }
    else if (y > second) second = y;
  }
  out[b] = (float)bj;
  out[NB + b] = expf(att[b * 28 + bj] - Mv[bj]) / Sv[bj];
  const int* mrow = mask + b * NL;
#pragma unroll
  for (int l = 0; l < NL; ++l)
    out[2 * NB + (size_t)b * NL + l] = (float)(mrow[l] - ((l == bj) ? 1 : 0));
  const int f = (best - second < GAP) ? 1 : 0;
  flag[b] = f;
  if (f) {
    int pos = atomicAdd(cnt, 1);
    if (pos < MAXF) list[pos] = b;
  }
}

// ---------------- build per-class (it, t) lists for flagged rows ----------
__global__ __launch_bounds__(256) void k_build_fl(
    const int* __restrict__ cnt, const int* __restrict__ list,
    const int* __restrict__ xes, int* __restrict__ fl_cnt,
    int* __restrict__ fl0, int* __restrict__ fl1) {
  const int it = blockIdx.x * 256 + threadIdx.x;
  const int n = (cnt[0] < MAXF) ? cnt[0] : MAXF;
  if (it >= n) return;
  const int b = list[it];
#pragma unroll
  for (int t = 0; t < NSTEP; ++t) {
    const int tt = xes[(b * NT + t) * 3 + 2];
    const int e = it * 8 + t;
    if (tt == 0) { int p = atomicAdd(&fl_cnt[0], 1); fl0[p] = e; }
    else         { int p = atomicAdd(&fl_cnt[1], 1); fl1[p] = e; }
  }
}

// ---------------- fp32 fixup: edges for flagged (it,t) pairs ----------------
__global__ __launch_bounds__(256) void k_fix_edge(
    const int* __restrict__ fl_cnt, const int* __restrict__ fl0,
    const int* __restrict__ fl1, const int* __restrict__ list,
    const int* __restrict__ xes, const float* __restrict__ enc,
    const float* __restrict__ Wh, const float* __restrict__ Wv,
    const float* __restrict__ Wsh, const float* __restrict__ Wsv,
    float* __restrict__ edgeF) {
  const int n0c = fl_cnt[0], n1c = fl_cnt[1];
  const int tiles0 = (n0c + 63) >> 6, tiles1 = (n1c + 63) >> 6;
  const int bx = blockIdx.x;
  if (bx >= tiles0 + tiles1) return;
  int cls, mtile, nc;
  const int* fl;
  if (bx < tiles0) { cls = 0; mtile = bx; nc = n0c; fl = fl0; }
  else { cls = 1; mtile = bx - tiles0; nc = n1c; fl = fl1; }

  __shared__ float As[16][68];
  __shared__ float Bs[16][68];
  float acc[4][4] = {};
  const int tid = threadIdx.x;
  const int tx = tid & 15, ty = tid >> 4;
  const int col0 = blockIdx.y * 64;
  const int lm = tid >> 2;
  const int lk4 = (tid & 3) * 4;

  const int li = mtile * 64 + lm;
  const int e = fl[(li < nc) ? li : (nc - 1)];
  const int it = e >> 3, t = e & 7;
  const int b = list[it];
  const int hidx = xes[(b * NT + t) * 3 + 0];
  const int vidx = xes[(b * NT + t) * 3 + 1];
  const float* arow0 = enc + (((size_t)b * NL + hidx) << 10);
  const float* arow1 = enc + (((size_t)b * NL + vidx) << 10);
  const float* W0 = (cls == 0) ? Wh : Wsh;
  const float* W1 = (cls == 0) ? Wv : Wsv;
  const float* brow0 = W0 + ((size_t)(col0 + lm) << 10);
  const float* brow1 = W1 + ((size_t)(col0 + lm) << 10);

  for (int half = 0; half < 2; ++half) {
    const float* ar = half ? arow1 : arow0;
    const float* br = half ? brow1 : brow0;
    for (int k0 = 0; k0 < ND; k0 += 16) {
      float4 av = *(const float4*)(ar + k0 + lk4);
      STORE_AS(av)
      float4 bv = *(const float4*)(br + k0 + lk4);
      STORE_BS(bv)
      __syncthreads();
      tile_compute(As, Bs, acc, tx, ty);
      __syncthreads();
    }
  }
#pragma unroll
  for (int i = 0; i < 4; ++i) {
    const int li2 = mtile * 64 + ty * 4 + i;
    if (li2 < nc) {
      const int e2 = fl[li2];
      const int it2 = e2 >> 3, t2 = e2 & 7;
      *(float4*)(edgeF + (((size_t)(it2 * 5 + t2)) << 10) + col0 + tx * 4) =
          make_float4(acc[i][0], acc[i][1], acc[i][2], acc[i][3]);
    }
  }
}

// ---------------- fp32 fixup: stF = max(0, max_t edgeF@We^T) --------------
__global__ __launch_bounds__(256) void k_fix_st(
    const int* __restrict__ cnt, const float* __restrict__ edgeF,
    const float* __restrict__ We, unsigned* __restrict__ stF) {
  const int n = (cnt[0] < MAXF) ? cnt[0] : MAXF;
  const int M = n * 5;
  const int tiles = (M + 63) >> 6;
  if ((int)blockIdx.x >= tiles) return;
  __shared__ float As[16][68];
  __shared__ float Bs[16][68];
  float acc[4][4] = {};
  const int tid = threadIdx.x;
  const int tx = tid & 15, ty = tid >> 4;
  const int row0 = blockIdx.x * 64, col0 = blockIdx.y * 64;
  const int lm = tid >> 2;
  const int lk4 = (tid & 3) * 4;
  const int r = row0 + lm;
  const int rc = (r < M) ? r : (M - 1);
  const float* arow = edgeF + ((size_t)rc << 10);
  const float* brow = We + ((size_t)(col0 + lm) << 10);
  for (int k0 = 0; k0 < NH; k0 += 16) {
    float4 av = *(const float4*)(arow + k0 + lk4);
    STORE_AS(av)
    float4 bv = *(const float4*)(brow + k0 + lk4);
    STORE_BS(bv)
    __syncthreads();
    tile_compute(As, Bs, acc, tx, ty);
    __syncthreads();
  }
#pragma unroll
  for (int i = 0; i < 4; ++i) {
    const int rr = row0 + ty * 4 + i;
    if (rr < M) {
      const int it = rr / 5;
#pragma unroll
      for (int j = 0; j < 4; ++j) {
        unsigned val = __float_as_uint(fmaxf(acc[i][j], 0.f));
        atomicMax(&stF[(size_t)it * NH + col0 + tx * 4 + j], val);
      }
    }
  }
}

// ---------------- fp32 fixup: query chain ----------------
__global__ __launch_bounds__(256) void k_fix_query(
    const int* __restrict__ cnt, const int* __restrict__ list,
    const float* __restrict__ edgeF, const float* __restrict__ stF,
    const float* __restrict__ lin, float* __restrict__ qF) {
  const int i = blockIdx.x * 256 + threadIdx.x;
  const int it = i >> 10;
  const int n = (cnt[0] < MAXF) ? cnt[0] : MAXF;
  if (it >= n) return;
  const int nn = i & (NH - 1);
  const int b = list[it];
  float e4 = edgeF[(((size_t)(it * 5 + 4)) << 10) + nn];
  float stv = stF[(size_t)it * NH + nn];
  float qt = fmaxf(e4 + stv, 0.f);
  float lb = lin[(size_t)b * NH + nn];
  float qv = fmaxf(fmaxf(qt + lb, 0.f) + lb, 0.f);
  qF[(size_t)it * NH + nn] = qv;
}

// ---------------- fp32 fixup: inp rows = qF @ Wq^T + bq -------------------
__global__ __launch_bounds__(256) void k_fix_inp(
    const int* __restrict__ cnt, const int* __restrict__ list,
    const float* __restrict__ qF, const float* __restrict__ Wq,
    const float* __restrict__ bq, float* __restrict__ inp) {
  const int n = (cnt[0] < MAXF) ? cnt[0] : MAXF;
  const int tiles = (n + 63) >> 6;
  if ((int)blockIdx.x >= tiles) return;
  __shared__ float As[16][68];
  __shared__ float Bs[16][68];
  float acc[4][4] = {};
  const int tid = threadIdx.x;
  const int tx = tid & 15, ty = tid >> 4;
  const int row0 = blockIdx.x * 64, col0 = blockIdx.y * 64;
  const int lm = tid >> 2;
  const int lk4 = (tid & 3) * 4;
  const int r = row0 + lm;
  const int rc = (r < n) ? r : (n - 1);
  const float* arow = qF + ((size_t)rc << 10);
  const float* brow = Wq + ((size_t)(col0 + lm) << 10);
  for (int k0 = 0; k0 < NH; k0 += 16) {
    float4 av = *(const float4*)(arow + k0 + lk4);
    STORE_AS(av)
    float4 bv = *(const float4*)(brow + k0 + lk4);
    STORE_BS(bv)
    __syncthreads();
    tile_compute(As, Bs, acc, tx, ty);
    __syncthreads();
  }
#pragma unroll
  for (int i = 0; i < 4; ++i) {
    const int rr = row0 + ty * 4 + i;
    if (rr < n) {
      const int b = list[rr];
      const int n0 = col0 + tx * 4;
      float4 v = make_float4(acc[i][0] + bq[n0 + 0], acc[i][1] + bq[n0 + 1],
                             acc[i][2] + bq[n0 + 2], acc[i][3] + bq[n0 + 3]);
      *(float4*)(inp + ((size_t)b << 10) + n0) = v;
    }
  }
}

// ---------------- fp32 att recompute for flagged rows ----------------
__global__ __launch_bounds__(256) void k_fixup_att(
    const int* __restrict__ cnt, const int* __restrict__ list,
    const float* __restrict__ enc, const float* __restrict__ Wc,
    const float* __restrict__ bc, const float* __restrict__ V4,
    const float* __restrict__ inp, const int* __restrict__ mask,
    float* __restrict__ att) {
  const int kq = blockIdx.x;
  const int tid = threadIdx.x;
  __shared__ float sEnc[NL][ND];
  __shared__ float sm[256];
  const int n = (cnt[0] < MAXF) ? cnt[0] : MAXF;
  for (int it = blockIdx.y; it < n; it += gridDim.y) {
    const int b = list[it];
    for (int i = tid; i < NL * 256; i += 256) {
      const int l = i >> 8, c = (i & 255) * 4;
      *(float4*)&sEnc[l][c] = *(const float4*)(enc + (((size_t)b * NL + l) << 10) + c);
    }
    __syncthreads();
    float accl[NL];
#pragma unroll
    for (int l = 0; l < NL; ++l) accl[l] = 0.f;
    for (int hp = 0; hp < 2; ++hp) {
      const int h0 = tid + hp * 512;
      const int h1 = h0 + 256;
      const float* w0 = Wc + (((size_t)kq * NH + h0) << 10);
      const float* w1 = Wc + (((size_t)kq * NH + h1) << 10);
      float d0[NL], d1[NL];
#pragma unroll
      for (int l = 0; l < NL; ++l) { d0[l] = 0.f; d1[l] = 0.f; }
      for (int k = 0; k < ND; k += 4) {
        float4 a = *(const float4*)(w0 + k);
        float4 c = *(const float4*)(w1 + k);
#pragma unroll
        for (int l = 0; l < NL; ++l) {
          float4 e = *(const float4*)&sEnc[l][k];
          d0[l] += a.x * e.x + a.y * e.y + a.z * e.z + a.w * e.w;
          d1[l] += c.x * e.x + c.y * e.y + c.z * e.z + c.w * e.w;
        }
      }
      const float i0 = inp[(size_t)b * NH + h0], i1 = inp[(size_t)b * NH + h1];
      const float b0 = bc[kq * NH + h0], b1 = bc[kq * NH + h1];
      const float v0 = V4[kq * NH + h0], v1 = V4[kq * NH + h1];
#pragma unroll
      for (int l = 0; l < NL; ++l)
        accl[l] += v0 * tanhf(d0[l] + i0 + b0) + v1 * tanhf(d1[l] + i1 + b1);
    }
    for (int l = 0; l < NL; ++l) {
      sm[tid] = accl[l];
      __syncthreads();
      for (int s = 128; s > 0; s >>= 1) {
        if (tid < s) sm[tid] += sm[tid + s];
        __syncthreads();
      }
      if (tid == 0) {
        float a = (mask[b * NL + l] != 0) ? (10.f * tanhf(sm[0])) : -10.f;
        att[b * 28 + kq * NL + l] = a;
      }
      __syncthreads();
    }
    __syncthreads();
  }
}

// ---------------- re-sample flagged rows with fixed att ----------------
__global__ __launch_bounds__(256) void k_resample(
    const int* __restrict__ flag, const float* __restrict__ att,
    const float* __restrict__ Mv, const float* __restrict__ Sv,
    const int* __restrict__ mask, float* __restrict__ out) {
  const int b = blockIdx.x * 256 + threadIdx.x;
  if (b >= NB) return;
  if (!flag[b]) return;
  float best = -INFINITY;
  int bj = 0;
  for (int j = 0; j < 28; ++j) {
    float y = (att[b * 28 + j] - Mv[j]) - logf(Sv[j]) + gumbel_for(b, j);
    if (y > best) { best = y; bj = j; }
  }
  out[b] = (float)bj;
  out[NB + b] = expf(att[b * 28 + bj] - Mv[bj]) / Sv[bj];
  const int* mrow = mask + b * NL;
#pragma unroll
  for (int l = 0; l < NL; ++l)
    out[2 * NB + (size_t)b * NL + l] = (float)(mrow[l] - ((l == bj) ? 1 : 0));
}

extern "C" void kernel_launch(void* const* d_in, const int* in_sizes, int n_in,
                              void* d_out, int out_size, void* d_ws, size_t ws_size,
                              hipStream_t stream) {
  const float* enc  = (const float*)d_in[0];
  const int*   xes  = (const int*)d_in[1];
  const int*   idx  = (const int*)d_in[2];
  const int*   mask = (const int*)d_in[3];
  const float* Wq   = (const float*)d_in[4];
  const float* bq   = (const float*)d_in[5];
  const float* Wc   = (const float*)d_in[6];
  const float* bc   = (const float*)d_in[7];
  const float* V4   = (const float*)d_in[8];
  const float* Wi   = (const float*)d_in[9];
  const float* bi   = (const float*)d_in[10];
  const float* Wh   = (const float*)d_in[11];
  const float* Wv   = (const float*)d_in[12];
  const float* Wsh  = (const float*)d_in[13];
  const float* Wsv  = (const float*)d_in[14];
  const float* We   = (const float*)d_in[15];
  (void)in_sizes; (void)n_in; (void)out_size; (void)ws_size;

  // ---- workspace layout (~350 MB) ----
  char* p = (char*)d_ws;
  float* edge4 = (float*)p;                 p += (size_t)NB * NH * 4;
  unsigned* ehilo = (unsigned*)p;           p += (size_t)NSTEP * NB * NH * 4;
  float* st = (float*)p;                    p += (size_t)NB * NH * 4;
  float* lin = (float*)p;                   p += (size_t)NB * NH * 4;
  float* inp = (float*)p;                   p += (size_t)NB * NH * 4;
  float* att = (float*)p;                   p += (size_t)NB * 28 * 4;
  float* Mv = (float*)p;                    p += 28 * 4;
  float* Sv = (float*)p;                    p += 28 * 4;
  int* flag = (int*)p;                      p += NB * 4;
  int* cnt = (int*)p;                       p += 4 * 4;
  int* list = (int*)p;                      p += NB * 4;
  int* cls_cnt = (int*)p;                   p += 2 * 4;
  int* l0 = (int*)p;                        p += NSTEP * NB * 4;
  int* l1 = (int*)p;                        p += NSTEP * NB * 4;
  int* fl_cnt = (int*)p;                    p += 2 * 4;
  int* fl0 = (int*)p;                       p += NSTEP * MAXF * 4;
  int* fl1 = (int*)p;                       p += NSTEP * MAXF * 4;
  float* edgeF = (float*)p;                 p += (size_t)NSTEP * MAXF * NH * 4;
  float* stF = (float*)p;                   p += (size_t)MAXF * NH * 4;
  float* qF = (float*)p;                    p += (size_t)MAXF * NH * 4;
  unsigned short* enc_hi = (unsigned short*)p; p += (size_t)NB * NL * ND * 2;
  unsigned short* enc_lo = (unsigned short*)p; p += (size_t)NB * NL * ND * 2;
  unsigned short* w4hi = (unsigned short*)p;   p += (size_t)4 * NH * ND * 2;
  unsigned short* w4lo = (unsigned short*)p;   p += (size_t)4 * NH * ND * 2;
  unsigned short* wehi = (unsigned short*)p;   p += (size_t)NH * ND * 2;
  unsigned short* welo = (unsigned short*)p;   p += (size_t)NH * ND * 2;
  unsigned short* wc_hi = (unsigned short*)p;  p += (size_t)4 * NH * ND * 2;
  unsigned short* wc_lo = (unsigned short*)p;  p += (size_t)4 * NH * ND * 2;
  unsigned short* wihi = (unsigned short*)p;   p += (size_t)NH * ND * 2;
  unsigned short* wilo = (unsigned short*)p;   p += (size_t)NH * ND * 2;
  unsigned short* wqhi = (unsigned short*)p;   p += (size_t)NH * ND * 2;
  unsigned short* wqlo = (unsigned short*)p;   p += (size_t)NH * ND * 2;
  unsigned short* qhi = (unsigned short*)p;    p += (size_t)NB * NH * 2;
  unsigned short* qlo = (unsigned short*)p;    p += (size_t)NB * NH * 2;
  float* out = (float*)d_out;

  hipMemsetAsync(st, 0, (size_t)NB * NH * sizeof(float), stream);
  hipMemsetAsync(att, 0, (size_t)NB * 28 * sizeof(float), stream);
  hipMemsetAsync(cnt, 0, sizeof(int), stream);
  hipMemsetAsync(cls_cnt, 0, 2 * sizeof(int), stream);
  hipMemsetAsync(fl_cnt, 0, 2 * sizeof(int), stream);
  hipMemsetAsync(stF, 0, (size_t)MAXF * NH * sizeof(float), stream);

  dim3 blk(256);
  // bf16 hi/lo planes
  k_split<<<dim3((NB * NL * ND) / 1024), blk, 0, stream>>>(enc, enc_hi, enc_lo);
  k_split<<<dim3((4 * NH * ND) / 1024), blk, 0, stream>>>(Wc, wc_hi, wc_lo);
  k_split<<<dim3((NH * ND) / 1024), blk, 0, stream>>>(Wh, w4hi, w4lo);
  k_split<<<dim3((NH * ND) / 1024), blk, 0, stream>>>(Wv, w4hi + (size_t)NH * ND, w4lo + (size_t)NH * ND);
  k_split<<<dim3((NH * ND) / 1024), blk, 0, stream>>>(Wsh, w4hi + (size_t)2 * NH * ND, w4lo + (size_t)2 * NH * ND);
  k_split<<<dim3((NH * ND) / 1024), blk, 0, stream>>>(Wsv, w4hi + (size_t)3 * NH * ND, w4lo + (size_t)3 * NH * ND);
  k_split<<<dim3((NH * ND) / 1024), blk, 0, stream>>>(We, wehi, welo);
  k_split<<<dim3((NH * ND) / 1024), blk, 0, stream>>>(Wi, wihi, wilo);
  k_split<<<dim3((NH * ND) / 1024), blk, 0, stream>>>(Wq, wqhi, wqlo);
  // classify rows by tt
  k_classify<<<dim3((NSTEP * NB) / 256), blk, 0, stream>>>(xes, cls_cnt, l0, l1);
  // edges via MFMA (K=2048, two classes, compacted); N-tile fastest
  g1_mfma<<<dim3(8, 162), blk, 0, stream>>>(cls_cnt, l0, l1, xes, enc_hi, enc_lo,
                                            w4hi, w4lo, ehilo, edge4);
  // lin = gather(enc, idx) @ Wi^T + bi via MFMA
  g_lin_mfma<<<dim3(8, 32), blk, 0, stream>>>(enc_hi, enc_lo, idx, wihi, wilo, bi, lin);
  // st = max(0, max_t edge@We^T) via MFMA; N-tile fastest
  g2_mfma<<<dim3(8, 160), blk, 0, stream>>>(ehilo, wehi, welo, (unsigned*)st);
  // query -> bf16 hi/lo planes
  k_query<<<dim3((NB * NH) / 1024), blk, 0, stream>>>(edge4, st, lin, qhi, qlo);
  // inp = query @ Wq^T + bq via MFMA
  g_lin_mfma<<<dim3(8, 32), blk, 0, stream>>>(qhi, qlo, nullptr, wqhi, wqlo, bq, inp);
  // att partial sums via bf16 MFMA (3-term hi/lo); N-tile fastest
  g5_mfma<<<dim3(32, 224), blk, 0, stream>>>(enc_hi, enc_lo, wc_hi, wc_lo,
                                             inp, bc, V4, att);
  k_finish<<<dim3((NB * 28) / 256), blk, 0, stream>>>(att, mask);
  k_colstats<<<dim3(28), blk, 0, stream>>>(att, Mv, Sv);
  k_sample<<<dim3(NB / 256), blk, 0, stream>>>(att, Mv, Sv, mask, out, flag, cnt, list);
  // fp32 fixup chain for flagged rows (GEMM-shaped, worst-case grids w/ early exit)
  k_build_fl<<<dim3(MAXF / 256), blk, 0, stream>>>(cnt, list, xes, fl_cnt, fl0, fl1);
  k_fix_edge<<<dim3(81, 16), blk, 0, stream>>>(fl_cnt, fl0, fl1, list, xes, enc,
                                               Wh, Wv, Wsh, Wsv, edgeF);
  k_fix_st<<<dim3(80, 16), blk, 0, stream>>>(cnt, edgeF, We, (unsigned*)stF);
  k_fix_query<<<dim3((MAXF * NH) / 256), blk, 0, stream>>>(cnt, list, edgeF, stF, lin, qF);
  k_fix_inp<<<dim3(16, 16), blk, 0, stream>>>(cnt, list, qF, Wq, bq, inp);
  k_fixup_att<<<dim3(4, 64), blk, 0, stream>>>(cnt, list, enc, Wc, bc, V4, inp, mask, att);
  k_resample<<<dim3(NB / 256), blk, 0, stream>>>(flag, att, Mv, Sv, mask, out);
}